// Round 10
// baseline (313.693 us; speedup 1.0000x reference)
//
#include <hip/hip_runtime.h>
#include <hip/hip_bf16.h>

#define NQ 4096
#define NK 8192
#define DQK 256
#define DA 64
#define NH 4
#define DOUT 256
#define NQT (NQ / 32)        // 128 q-tiles of 32
#define NSUP 8               // surviving partials per (h,qt): 8 key-regions
#define LOG2E 1.44269504088896340736f
#define QSCALE (0.125f * LOG2E)   // 1/sqrt(64) * log2(e), folded into Qp

typedef __attribute__((ext_vector_type(8))) short bf16x8;
typedef __attribute__((ext_vector_type(4))) float f32x4;
typedef __attribute__((ext_vector_type(2))) _Float16 f16x2;
typedef __attribute__((ext_vector_type(4))) _Float16 f16x4;
typedef __attribute__((ext_vector_type(8))) _Float16 f16x8;

// native HW packed bf16 convert via inline asm (no builtin on gfx950;
// __hip_bfloat16 types are not trivially copyable -> no bit_cast)
__device__ inline unsigned cvt2bf(float a, float b) {
  unsigned r;
  asm("v_cvt_pk_bf16_f32 %0, %1, %2" : "=v"(r) : "v"(a), "v"(b));
  return r;
}

__device__ inline unsigned short f2bf(float f) {
  return (unsigned short)(cvt2bf(f, 0.f) & 0xffffu);
}

__device__ inline f16x2 pkrtz(float a, float b) {
  return __builtin_bit_cast(f16x2, __builtin_amdgcn_cvt_pkrtz(a, b));
}

__device__ inline void gload16(const void* g, void* l) {
  __builtin_amdgcn_global_load_lds(
      (const __attribute__((address_space(1))) void*)g,
      (__attribute__((address_space(3))) void*)l, 16, 0, 0);
}

// ---------------------------------------------------------------------------
// 1. mask (int32 NQ x NK) -> TRANSPOSED bitmask bitsT[word32][row] (4 MB).
// ---------------------------------------------------------------------------
__global__ __launch_bounds__(256) void maskbits_kernel(
    const int* __restrict__ mask, unsigned* __restrict__ bitsT) {
  const int NW = 8192 * 4;                       // total waves
  int wid = blockIdx.x * 4 + (threadIdx.x >> 6);
  int lane = threadIdx.x & 63;
  for (int j = 0; j < 2; ++j) {
    int v[8];
#pragma unroll
    for (int u = 0; u < 8; ++u) {
      int c = wid + (j * 8 + u) * NW;   // u64 chunk id: row = c>>7, ch = c&127
      v[u] = mask[(size_t)(c >> 7) * NK + (c & 127) * 64 + lane];
    }
#pragma unroll
    for (int u = 0; u < 8; ++u) {
      unsigned long long b = __ballot(v[u] != 0);
      int c = wid + (j * 8 + u) * NW;
      int n = c >> 7, ch = c & 127;
      if (lane == 0)  bitsT[(size_t)(2 * ch) * NQ + n] = (unsigned)b;
      if (lane == 32) bitsT[(size_t)(2 * ch + 1) * NQ + n] = (unsigned)(b >> 32);
    }
  }
}

// ---------------------------------------------------------------------------
// 2. projections — all f32->bf16 via native v_cvt_pk_bf16_f32.
// ---------------------------------------------------------------------------
__global__ __launch_bounds__(256) void proj_kernel(
    const float* __restrict__ xQ, const float* __restrict__ xK,
    const float* __restrict__ Wq, const float* __restrict__ Wk,
    const float* __restrict__ Wv,
    unsigned short* __restrict__ Qp, unsigned short* __restrict__ Kp,
    _Float16* __restrict__ Vf) {
  __shared__ __align__(16) unsigned short Wt[64][264];  // Wt[d][c], padded

  int b = blockIdx.x;
  int proj, h, rb;
  if (b < 128)       { proj = 0; h = b >> 5;  rb = b & 31; }
  else if (b < 384)  { proj = 1; b -= 128; h = b >> 6; rb = b & 63; }
  else               { proj = 2; b -= 384; h = b >> 6; rb = b & 63; }
  const float* x = (proj == 0) ? xQ : xK;
  const float* W = (proj == 0 ? Wq : (proj == 1 ? Wk : Wv)) + (size_t)h * 256 * 64;

  for (int i = threadIdx.x; i < 16384; i += 256)
    Wt[i & 63][i >> 6] = f2bf(W[i]);
  __syncthreads();

  int lane = threadIdx.x & 63, wv = threadIdx.x >> 6;
  int quad = lane >> 4, n16 = lane & 15;
  int r0 = rb * 128 + wv * 32;          // 32 rows per wave

  f32x4 acc[2][4];
#pragma unroll
  for (int mt = 0; mt < 2; ++mt)
#pragma unroll
    for (int nt = 0; nt < 4; ++nt)
      acc[mt][nt] = (f32x4){0.f, 0.f, 0.f, 0.f};

#pragma unroll
  for (int it = 0; it < 8; ++it) {
    const int k0 = it * 32;
    bf16x8 af[2];
#pragma unroll
    for (int mt = 0; mt < 2; ++mt) {
      const float* xp = x + (size_t)(r0 + mt * 16 + n16) * 256 + k0 + quad * 8;
      const float4 a0 = *(const float4*)xp;
      const float4 a1 = *(const float4*)(xp + 4);
      union { bf16x8 v; unsigned u[4]; } a;
      a.u[0] = cvt2bf(a0.x, a0.y);
      a.u[1] = cvt2bf(a0.z, a0.w);
      a.u[2] = cvt2bf(a1.x, a1.y);
      a.u[3] = cvt2bf(a1.z, a1.w);
      af[mt] = a.v;
    }
    bf16x8 bfr[4];
#pragma unroll
    for (int nt = 0; nt < 4; ++nt)
      bfr[nt] = *(const bf16x8*)&Wt[nt * 16 + n16][k0 + quad * 8];
#pragma unroll
    for (int mt = 0; mt < 2; ++mt)
#pragma unroll
      for (int nt = 0; nt < 4; ++nt)
        acc[mt][nt] = __builtin_amdgcn_mfma_f32_16x16x32_bf16(
            af[mt], bfr[nt], acc[mt][nt], 0, 0, 0);
  }

  if (proj < 2) {
    unsigned short* outp =
        (proj == 0 ? Qp : Kp) + (size_t)h * (size_t)(proj == 0 ? NQ : NK) * 64;
    const float sc = (proj == 0) ? QSCALE : 1.0f;
#pragma unroll
    for (int mt = 0; mt < 2; ++mt)
#pragma unroll
      for (int nt = 0; nt < 4; ++nt) {
        unsigned p0 = cvt2bf(acc[mt][nt][0] * sc, acc[mt][nt][1] * sc);
        unsigned p1 = cvt2bf(acc[mt][nt][2] * sc, acc[mt][nt][3] * sc);
        int row = r0 + mt * 16 + quad * 4;
        int col = nt * 16 + n16;
        outp[(size_t)row * 64 + col] = (unsigned short)(p0 & 0xffffu);
        outp[(size_t)(row + 1) * 64 + col] = (unsigned short)(p0 >> 16);
        outp[(size_t)(row + 2) * 64 + col] = (unsigned short)(p1 & 0xffffu);
        outp[(size_t)(row + 3) * 64 + col] = (unsigned short)(p1 >> 16);
      }
  } else {
    // K=32 fragment-linear V: tile = h*256 + keyblock32
    int tile = h * 256 + (r0 >> 5);
#pragma unroll
    for (int nt = 0; nt < 4; ++nt) {
      f16x8 pk;
      pk[0] = (_Float16)acc[0][nt][0]; pk[1] = (_Float16)acc[0][nt][1];
      pk[2] = (_Float16)acc[0][nt][2]; pk[3] = (_Float16)acc[0][nt][3];
      pk[4] = (_Float16)acc[1][nt][0]; pk[5] = (_Float16)acc[1][nt][1];
      pk[6] = (_Float16)acc[1][nt][2]; pk[7] = (_Float16)acc[1][nt][3];
      *(f16x8*)&Vf[(((size_t)tile * 4 + nt) * 64 + lane) * 8] = pk;
    }
  }
}

// ---------------------------------------------------------------------------
// 3. flash attention — EXACT round-6 version (best measured: 294.1 total).
//    Depth-2 async pipeline, 32-key tiles, 3 LDS buffers, qc=2,
//    grid 1024 = 4 blocks/CU.
// ---------------------------------------------------------------------------
__global__ __launch_bounds__(256, 4) void attn_kernel(
    const unsigned short* __restrict__ Qp, const unsigned short* __restrict__ Kp,
    const _Float16* __restrict__ Vf, const unsigned* __restrict__ bitsT,
    _Float16* __restrict__ Opart, float* __restrict__ Lpart) {
  __shared__ __align__(16) char lds[3][8192];   // [buf][K 4KB | V 4KB]

  // bijective XCD swizzle (8 XCDs, 1024 blocks, 128/chunk)
  int orig = blockIdx.x;
  int wgid = (orig & 7) * 128 + (orig >> 3);
  int qtg = wgid & 31;
  int combo = wgid >> 5;          // h*8 + kp: each XCD owns 4 combos, same h
  int kp = combo & 7, h = combo >> 3;

  int wv = threadIdx.x >> 6, lane = threadIdx.x & 63;
  int quad = lane >> 4, n16 = lane & 15;
  int qt = qtg * 4 + wv;          // this wave's q-tile
  int qb = qt * 32;

  // Q frags (bf16, pre-scaled by QSCALE)
  bf16x8 qf[2][2];
#pragma unroll
  for (int qc = 0; qc < 2; ++qc)
#pragma unroll
    for (int c = 0; c < 2; ++c)
      qf[qc][c] = *(const bf16x8*)&Qp[((size_t)h * NQ + qb + qc * 16 + n16) * 64 +
                                      c * 32 + quad * 8];

  f32x4 o[4][2];
#pragma unroll
  for (int dt = 0; dt < 4; ++dt)
#pragma unroll
    for (int qc = 0; qc < 2; ++qc) o[dt][qc] = (f32x4){0.f, 0.f, 0.f, 0.f};
  f32x4 o_l[2];
  o_l[0] = (f32x4){0.f, 0.f, 0.f, 0.f};
  o_l[1] = (f32x4){0.f, 0.f, 0.f, 0.f};

  f16x8 vones;
#pragma unroll
  for (int i = 0; i < 8; ++i) vones[i] = (_Float16)1.0f;

  const char* Kreg = (const char*)(Kp + (size_t)h * NK * 64 + (size_t)kp * 1024 * 64);
  const char* Vreg = (const char*)(Vf + ((size_t)h * 256 + kp * 32) * 2048);
  const unsigned* bT = bitsT + (size_t)(kp * 32) * NQ + qb;

  // per-lane source offsets: each wave stages 2 KB of the 8 KB tile image.
  const char* sb;
  int soff[2];
  if (wv < 2) {
    sb = Kreg;
#pragma unroll
    for (int i = 0; i < 2; ++i)
      soff[i] = ((wv * 16 + n16) * 64 + i * 32 + quad * 8) * 2;
  } else {
    sb = Vreg;
#pragma unroll
    for (int i = 0; i < 2; ++i)
      soff[i] = (wv - 2) * 2048 + i * 1024 + lane * 16;
  }

  auto stage = [&](int t, int bufidx) {
    char* d = &lds[bufidx][wv * 2048];
    const char* s0 = sb + (size_t)t * 4096;
#pragma unroll
    for (int i = 0; i < 2; ++i)
      gload16(s0 + soff[i], d + i * 1024);
  };

  auto compute = [&](int buf, unsigned wqa0, unsigned wqa1) {
    const char* Kl = lds[buf];
    const char* Vl = lds[buf] + 4096;

    bf16x8 kf[2][2];
#pragma unroll
    for (int kr = 0; kr < 2; ++kr)
#pragma unroll
      for (int c = 0; c < 2; ++c)
        kf[kr][c] = *(const bf16x8*)(Kl + (kr * 2 + c) * 1024 + lane * 16);

    // S^T = K·Q^T (bf16 K=32, pre-scaled)
    f32x4 s[2][2];
#pragma unroll
    for (int kr = 0; kr < 2; ++kr)
#pragma unroll
      for (int qc = 0; qc < 2; ++qc) {
        f32x4 acc = (f32x4){0.f, 0.f, 0.f, 0.f};
        acc = __builtin_amdgcn_mfma_f32_16x16x32_bf16(kf[kr][0], qf[qc][0], acc, 0, 0, 0);
        acc = __builtin_amdgcn_mfma_f32_16x16x32_bf16(kf[kr][1], qf[qc][1], acc, 0, 0, 0);
        s[kr][qc] = acc;
      }

    f16x8 vf8[4];
#pragma unroll
    for (int dt = 0; dt < 4; ++dt)
      vf8[dt] = *(const f16x8*)(Vl + dt * 1024 + lane * 16);

#pragma unroll
    for (int qc = 0; qc < 2; ++qc) {
      unsigned wq = (qc == 0 ? wqa0 : wqa1) >> (quad * 4);
      union { f16x8 v; f16x2 h[4]; } pu;
#pragma unroll
      for (int kr = 0; kr < 2; ++kr) {
        float e0 = __builtin_amdgcn_exp2f(s[kr][qc][0]);
        float e1 = __builtin_amdgcn_exp2f(s[kr][qc][1]);
        float e2 = __builtin_amdgcn_exp2f(s[kr][qc][2]);
        float e3 = __builtin_amdgcn_exp2f(s[kr][qc][3]);
        e0 = (wq & (1u << (kr * 16 + 0))) ? e0 : 0.f;
        e1 = (wq & (1u << (kr * 16 + 1))) ? e1 : 0.f;
        e2 = (wq & (1u << (kr * 16 + 2))) ? e2 : 0.f;
        e3 = (wq & (1u << (kr * 16 + 3))) ? e3 : 0.f;
        pu.h[kr * 2 + 0] = pkrtz(e0, e1);
        pu.h[kr * 2 + 1] = pkrtz(e2, e3);
      }
      // l-sum on the MFMA pipe: ones-A-frag, every reg = sum_k P[k][q]
      o_l[qc] = __builtin_amdgcn_mfma_f32_16x16x32_f16(vones, pu.v, o_l[qc], 0, 0, 0);
#pragma unroll
      for (int dt = 0; dt < 4; ++dt)
        o[dt][qc] = __builtin_amdgcn_mfma_f32_16x16x32_f16(vf8[dt], pu.v,
                                                           o[dt][qc], 0, 0, 0);
    }
  };

  // ---- prologue: bits(0), stage(0), stage(1); wait stage(0) only
  unsigned cw0 = bT[n16], cw1 = bT[16 + n16];
  stage(0, 0);
  stage(1, 1);
  asm volatile("s_waitcnt vmcnt(2)" ::: "memory");
  __builtin_amdgcn_sched_barrier(0);
  __builtin_amdgcn_s_barrier();

  // ---- main loop: 30 full-pipeline tiles (unroll 3 -> constant buf indices)
#pragma unroll 3
  for (int t = 0; t < 30; ++t) {
    stage(t + 2, (t + 2) % 3);
    unsigned nw0 = bT[(size_t)(t + 1) * NQ + n16];
    unsigned nw1 = bT[(size_t)(t + 1) * NQ + 16 + n16];
    compute(t % 3, cw0, cw1);
    cw0 = nw0; cw1 = nw1;
    asm volatile("s_waitcnt vmcnt(4)" ::: "memory");
    __builtin_amdgcn_sched_barrier(0);
    __builtin_amdgcn_s_barrier();
  }
  // t = 30: no stage; wait stage(31)
  {
    unsigned nw0 = bT[(size_t)31 * NQ + n16];
    unsigned nw1 = bT[(size_t)31 * NQ + 16 + n16];
    compute(0, cw0, cw1);
    cw0 = nw0; cw1 = nw1;
    asm volatile("s_waitcnt vmcnt(2)" ::: "memory");
    __builtin_amdgcn_sched_barrier(0);
    __builtin_amdgcn_s_barrier();
  }
  // t = 31: compute only
  compute(1, cw0, cw1);

  // ---- direct per-wave store (no cross-wave reduction needed)
  const size_t tile = ((size_t)h * NQT + qt) * NSUP + kp;
#pragma unroll
  for (int qc = 0; qc < 2; ++qc) {
#pragma unroll
    for (int dt = 0; dt < 4; ++dt) {
      union { f16x4 v; f16x2 h[2]; } u;
      u.h[0] = pkrtz(o[dt][qc][0], o[dt][qc][1]);
      u.h[1] = pkrtz(o[dt][qc][2], o[dt][qc][3]);
      *(f16x4*)&Opart[(tile * 32 + qc * 16 + n16) * 64 + dt * 16 + quad * 4] = u.v;
    }
    if (quad == 0) Lpart[tile * 32 + qc * 16 + n16] = o_l[qc][0];
  }
}

// ---------------------------------------------------------------------------
// 4. combine (r8 version, validated): fully-coalesced Opart reads.
//    Wave = one head; per (h,s) each lane reads f16x8 (16B) so one
//    wave-load covers the block's 8 rows x 64 a slab (1 KB contiguous).
//    Phased LDS reduce across the 4 head-waves, then @Wo + bo.
// ---------------------------------------------------------------------------
__global__ __launch_bounds__(256) void combine_kernel(
    const _Float16* __restrict__ Opart, const float* __restrict__ Lpart,
    const float* __restrict__ xQ, const float* __restrict__ Wg,
    const float* __restrict__ bg, const float* __restrict__ Wo,
    const float* __restrict__ bo, float* __restrict__ out) {
  __shared__ float comb[8][68];   // +4 pad: conflict-free phased writes
  __shared__ float gred[32][8];
  __shared__ float glds[8][4];
  int nb = blockIdx.x;
  int tid = threadIdx.x;
  int row0 = nb * 8;

  // gates for this block's 8 rows x 4 heads (32 dots, 8-way split each)
  {
    int rh = tid >> 3, c = tid & 7;
    int r = rh >> 2, hh = rh & 3;
    const float* xp = xQ + (size_t)(row0 + r) * 256 + c * 32;
    const float* wp = Wg + hh * 256 + c * 32;
    float s = 0.f;
#pragma unroll
    for (int e = 0; e < 32; ++e) s = fmaf(xp[e], wp[e], s);
    gred[rh][c] = s;
  }
  __syncthreads();
  if (tid < 32) {
    float s = 0.f;
#pragma unroll
    for (int c = 0; c < 8; ++c) s += gred[tid][c];
    glds[tid >> 2][tid & 3] = 1.f / (1.f + __expf(-(s + bg[tid & 3])));
  }
  __syncthreads();

  int wv = tid >> 6, lane = tid & 63;
  int rr = lane >> 3, a8 = lane & 7;    // lane covers (row rr, a-octet a8)
  int qt = nb >> 2, rbase = (nb & 3) * 8;
  int hh = wv;                          // wave = head

  float o8[8];
#pragma unroll
  for (int j = 0; j < 8; ++j) o8[j] = 0.f;
  float lt = 0.f;
  size_t t0 = ((size_t)hh * NQT + qt) * NSUP;
#pragma unroll
  for (int s = 0; s < NSUP; ++s) {
    size_t t = t0 + s;
    // lane*8 = rr*64 + a8*8: element (row rbase+rr, a = a8*8+j). 1KB/wave.
    f16x8 v = *(const f16x8*)&Opart[(t * 32 + rbase) * 64 + lane * 8];
#pragma unroll
    for (int j = 0; j < 8; ++j) o8[j] += (float)v[j];
    lt += Lpart[t * 32 + rbase + rr];
  }
  float g = glds[rr][hh] / lt;

  // phased reduction across the 4 head-waves
#pragma unroll
  for (int w = 0; w < 4; ++w) {
    if (wv == w) {
      if (w == 0) {
#pragma unroll
        for (int j = 0; j < 8; ++j) comb[rr][a8 * 8 + j] = g * o8[j];
      } else {
#pragma unroll
        for (int j = 0; j < 8; ++j) comb[rr][a8 * 8 + j] += g * o8[j];
      }
    }
    __syncthreads();
  }

  int j = tid;
  float accv[8];
#pragma unroll
  for (int r = 0; r < 8; ++r) accv[r] = bo[j];
  for (int aa = 0; aa < 64; ++aa) {
    float w = Wo[(size_t)aa * 256 + j];
#pragma unroll
    for (int r = 0; r < 8; ++r) accv[r] = fmaf(comb[r][aa], w, accv[r]);
  }
#pragma unroll
  for (int r = 0; r < 8; ++r)
    out[(size_t)(row0 + r) * 256 + j] = accv[r];
}

// ---------------------------------------------------------------------------
extern "C" void kernel_launch(void* const* d_in, const int* in_sizes, int n_in,
                              void* d_out, int out_size, void* d_ws, size_t ws_size,
                              hipStream_t stream) {
  const float* xQ  = (const float*)d_in[0];
  const float* xK  = (const float*)d_in[1];
  const int*   mask= (const int*)d_in[2];
  const float* Wq  = (const float*)d_in[3];
  const float* Wk  = (const float*)d_in[4];
  const float* Wv  = (const float*)d_in[5];
  const float* Wg  = (const float*)d_in[6];
  const float* bg  = (const float*)d_in[7];
  const float* Wo  = (const float*)d_in[8];
  const float* bo  = (const float*)d_in[9];
  float* out = (float*)d_out;

  char* ws = (char*)d_ws;
  unsigned short* Qp   = (unsigned short*)(ws + 0);         // 2 MB   [H][NQ][64]
  unsigned short* Kp   = (unsigned short*)(ws + 2097152);   // 4 MB   [H][NK][64]
  _Float16*       Vfp  = (_Float16*)(ws + 6291456);         // 4 MB   frag-linear
  unsigned*       bitsT= (unsigned*)(ws + 10485760);        // 4 MB   [word][row]
  float*          Lp   = (float*)(ws + 14680064);           // 512 KB (4096 tiles)
  _Float16*       Op   = (_Float16*)(ws + 15204352);        // 16.8 MB f16

  maskbits_kernel<<<dim3(8192), dim3(256), 0, stream>>>(mask, bitsT);
  proj_kernel<<<dim3(640), dim3(256), 0, stream>>>(xQ, xK, Wq, Wk, Wv, Qp, Kp, Vfp);
  attn_kernel<<<dim3(1024), dim3(256), 0, stream>>>(Qp, Kp, Vfp, bitsT, Op, Lp);
  combine_kernel<<<dim3(NQ / 8), dim3(256), 0, stream>>>(Op, Lp, xQ, Wg, bg,
                                                         Wo, bo, out);
}

// Round 11
// 299.549 us; speedup vs baseline: 1.0472x; 1.0472x over previous
//
#include <hip/hip_runtime.h>
#include <hip/hip_bf16.h>

#define NQ 4096
#define NK 8192
#define DQK 256
#define DA 64
#define NH 4
#define DOUT 256
#define NQT (NQ / 32)        // 128 q-tiles of 32
#define NSUP 8               // surviving partials per (h,qt): 8 key-regions
#define LOG2E 1.44269504088896340736f
#define QSCALE (0.125f * LOG2E)   // 1/sqrt(64) * log2(e), folded into Qp

typedef __attribute__((ext_vector_type(8))) short bf16x8;
typedef __attribute__((ext_vector_type(4))) float f32x4;
typedef __attribute__((ext_vector_type(2))) _Float16 f16x2;
typedef __attribute__((ext_vector_type(4))) _Float16 f16x4;
typedef __attribute__((ext_vector_type(8))) _Float16 f16x8;

// manual RNE f32->bf16 (r6-proven; m240: do NOT hand-write v_cvt_pk asm)
__device__ inline unsigned short f2bf(float f) {
  union { float f; unsigned u; } v; v.f = f;
  unsigned r = v.u + 0x7fff + ((v.u >> 16) & 1);  // RNE
  return (unsigned short)(r >> 16);
}

__device__ inline f16x2 pkrtz(float a, float b) {
  return __builtin_bit_cast(f16x2, __builtin_amdgcn_cvt_pkrtz(a, b));
}

__device__ inline void gload16(const void* g, void* l) {
  __builtin_amdgcn_global_load_lds(
      (const __attribute__((address_space(1))) void*)g,
      (__attribute__((address_space(3))) void*)l, 16, 0, 0);
}

// ---------------------------------------------------------------------------
// 1. mask (int32 NQ x NK) -> TRANSPOSED bitmask bitsT[word32][row] (4 MB).
// ---------------------------------------------------------------------------
__global__ __launch_bounds__(256) void maskbits_kernel(
    const int* __restrict__ mask, unsigned* __restrict__ bitsT) {
  const int NW = 8192 * 4;                       // total waves
  int wid = blockIdx.x * 4 + (threadIdx.x >> 6);
  int lane = threadIdx.x & 63;
  for (int j = 0; j < 2; ++j) {
    int v[8];
#pragma unroll
    for (int u = 0; u < 8; ++u) {
      int c = wid + (j * 8 + u) * NW;   // u64 chunk id: row = c>>7, ch = c&127
      v[u] = mask[(size_t)(c >> 7) * NK + (c & 127) * 64 + lane];
    }
#pragma unroll
    for (int u = 0; u < 8; ++u) {
      unsigned long long b = __ballot(v[u] != 0);
      int c = wid + (j * 8 + u) * NW;
      int n = c >> 7, ch = c & 127;
      if (lane == 0)  bitsT[(size_t)(2 * ch) * NQ + n] = (unsigned)b;
      if (lane == 32) bitsT[(size_t)(2 * ch + 1) * NQ + n] = (unsigned)(b >> 32);
    }
  }
}

// ---------------------------------------------------------------------------
// 2. projections, KV-FUSED: blocks 0..127 = Q (exact r6 path);
//    blocks 128..383 = K+V fused — each xK row-fragment is loaded ONCE into
//    registers and feeds BOTH Wk and Wv MFMA accumulators (two W tiles in
//    LDS). Halves the KV x-stream (64 -> 32 MB) and amortizes load latency
//    over 2x the MFMA work.
// ---------------------------------------------------------------------------
__global__ __launch_bounds__(256) void proj_kernel(
    const float* __restrict__ xQ, const float* __restrict__ xK,
    const float* __restrict__ Wq, const float* __restrict__ Wk,
    const float* __restrict__ Wv,
    unsigned short* __restrict__ Qp, unsigned short* __restrict__ Kp,
    _Float16* __restrict__ Vf) {
  __shared__ __align__(16) unsigned short WtA[64][264];  // Wt[d][c], padded
  __shared__ __align__(16) unsigned short WtB[64][264];

  int b = blockIdx.x;
  int lane = threadIdx.x & 63, wv = threadIdx.x >> 6;
  int quad = lane >> 4, n16 = lane & 15;

  if (b < 128) {
    // ---------------- Q path (exact r6) ----------------
    int h = b >> 5, rb = b & 31;
    const float* W = Wq + (size_t)h * 256 * 64;
    for (int i = threadIdx.x; i < 16384; i += 256)
      WtA[i & 63][i >> 6] = f2bf(W[i]);
    __syncthreads();

    int r0 = rb * 128 + wv * 32;
    f32x4 acc[2][4];
#pragma unroll
    for (int mt = 0; mt < 2; ++mt)
#pragma unroll
      for (int nt = 0; nt < 4; ++nt)
        acc[mt][nt] = (f32x4){0.f, 0.f, 0.f, 0.f};

#pragma unroll
    for (int it = 0; it < 8; ++it) {
      const int k0 = it * 32;
      bf16x8 af[2];
#pragma unroll
      for (int mt = 0; mt < 2; ++mt) {
        const float* xp = xQ + (size_t)(r0 + mt * 16 + n16) * 256 + k0 + quad * 8;
        const float4 a0 = *(const float4*)xp;
        const float4 a1 = *(const float4*)(xp + 4);
        bf16x8 a;
        a[0] = (short)f2bf(a0.x); a[1] = (short)f2bf(a0.y);
        a[2] = (short)f2bf(a0.z); a[3] = (short)f2bf(a0.w);
        a[4] = (short)f2bf(a1.x); a[5] = (short)f2bf(a1.y);
        a[6] = (short)f2bf(a1.z); a[7] = (short)f2bf(a1.w);
        af[mt] = a;
      }
      bf16x8 bfr[4];
#pragma unroll
      for (int nt = 0; nt < 4; ++nt)
        bfr[nt] = *(const bf16x8*)&WtA[nt * 16 + n16][k0 + quad * 8];
#pragma unroll
      for (int mt = 0; mt < 2; ++mt)
#pragma unroll
        for (int nt = 0; nt < 4; ++nt)
          acc[mt][nt] = __builtin_amdgcn_mfma_f32_16x16x32_bf16(
              af[mt], bfr[nt], acc[mt][nt], 0, 0, 0);
    }

    unsigned short* outp = Qp + (size_t)h * NQ * 64;
#pragma unroll
    for (int mt = 0; mt < 2; ++mt)
#pragma unroll
      for (int nt = 0; nt < 4; ++nt)
#pragma unroll
        for (int r = 0; r < 4; ++r) {
          int row = r0 + mt * 16 + quad * 4 + r;
          int col = nt * 16 + n16;
          outp[(size_t)row * 64 + col] = f2bf(acc[mt][nt][r] * QSCALE);
        }
  } else {
    // ---------------- fused K+V path ----------------
    int b2 = b - 128;
    int h = b2 >> 6, rb = b2 & 63;
    const float* WkH = Wk + (size_t)h * 256 * 64;
    const float* WvH = Wv + (size_t)h * 256 * 64;
    for (int i = threadIdx.x; i < 16384; i += 256) {
      WtA[i & 63][i >> 6] = f2bf(WkH[i]);
      WtB[i & 63][i >> 6] = f2bf(WvH[i]);
    }
    __syncthreads();

    int r0 = rb * 128 + wv * 32;
    f32x4 accK[2][4], accV[2][4];
#pragma unroll
    for (int mt = 0; mt < 2; ++mt)
#pragma unroll
      for (int nt = 0; nt < 4; ++nt) {
        accK[mt][nt] = (f32x4){0.f, 0.f, 0.f, 0.f};
        accV[mt][nt] = (f32x4){0.f, 0.f, 0.f, 0.f};
      }

#pragma unroll
    for (int it = 0; it < 8; ++it) {
      const int k0 = it * 32;
      bf16x8 af[2];
#pragma unroll
      for (int mt = 0; mt < 2; ++mt) {
        const float* xp = xK + (size_t)(r0 + mt * 16 + n16) * 256 + k0 + quad * 8;
        const float4 a0 = *(const float4*)xp;
        const float4 a1 = *(const float4*)(xp + 4);
        bf16x8 a;
        a[0] = (short)f2bf(a0.x); a[1] = (short)f2bf(a0.y);
        a[2] = (short)f2bf(a0.z); a[3] = (short)f2bf(a0.w);
        a[4] = (short)f2bf(a1.x); a[5] = (short)f2bf(a1.y);
        a[6] = (short)f2bf(a1.z); a[7] = (short)f2bf(a1.w);
        af[mt] = a;
      }
      bf16x8 bfrK[4], bfrV[4];
#pragma unroll
      for (int nt = 0; nt < 4; ++nt) {
        bfrK[nt] = *(const bf16x8*)&WtA[nt * 16 + n16][k0 + quad * 8];
        bfrV[nt] = *(const bf16x8*)&WtB[nt * 16 + n16][k0 + quad * 8];
      }
#pragma unroll
      for (int mt = 0; mt < 2; ++mt)
#pragma unroll
        for (int nt = 0; nt < 4; ++nt) {
          accK[mt][nt] = __builtin_amdgcn_mfma_f32_16x16x32_bf16(
              af[mt], bfrK[nt], accK[mt][nt], 0, 0, 0);
          accV[mt][nt] = __builtin_amdgcn_mfma_f32_16x16x32_bf16(
              af[mt], bfrV[nt], accV[mt][nt], 0, 0, 0);
        }
    }

    // K epilogue (row-major bf16)
    unsigned short* outp = Kp + (size_t)h * NK * 64;
#pragma unroll
    for (int mt = 0; mt < 2; ++mt)
#pragma unroll
      for (int nt = 0; nt < 4; ++nt)
#pragma unroll
        for (int r = 0; r < 4; ++r) {
          int row = r0 + mt * 16 + quad * 4 + r;
          int col = nt * 16 + n16;
          outp[(size_t)row * 64 + col] = f2bf(accK[mt][nt][r]);
        }

    // V epilogue: K=32 fragment-linear, tile = h*256 + keyblock32
    int tile = h * 256 + (r0 >> 5);
#pragma unroll
    for (int nt = 0; nt < 4; ++nt) {
      f16x8 pk;
      pk[0] = (_Float16)accV[0][nt][0]; pk[1] = (_Float16)accV[0][nt][1];
      pk[2] = (_Float16)accV[0][nt][2]; pk[3] = (_Float16)accV[0][nt][3];
      pk[4] = (_Float16)accV[1][nt][0]; pk[5] = (_Float16)accV[1][nt][1];
      pk[6] = (_Float16)accV[1][nt][2]; pk[7] = (_Float16)accV[1][nt][3];
      *(f16x8*)&Vf[(((size_t)tile * 4 + nt) * 64 + lane) * 8] = pk;
    }
  }
}

// ---------------------------------------------------------------------------
// 3. flash attention — EXACT round-6 version (best measured: 294.1 total).
//    Depth-2 async pipeline, 32-key tiles, 3 LDS buffers, qc=2,
//    grid 1024 = 4 blocks/CU.
// ---------------------------------------------------------------------------
__global__ __launch_bounds__(256, 4) void attn_kernel(
    const unsigned short* __restrict__ Qp, const unsigned short* __restrict__ Kp,
    const _Float16* __restrict__ Vf, const unsigned* __restrict__ bitsT,
    _Float16* __restrict__ Opart, float* __restrict__ Lpart) {
  __shared__ __align__(16) char lds[3][8192];   // [buf][K 4KB | V 4KB]

  // bijective XCD swizzle (8 XCDs, 1024 blocks, 128/chunk)
  int orig = blockIdx.x;
  int wgid = (orig & 7) * 128 + (orig >> 3);
  int qtg = wgid & 31;
  int combo = wgid >> 5;          // h*8 + kp: each XCD owns 4 combos, same h
  int kp = combo & 7, h = combo >> 3;

  int wv = threadIdx.x >> 6, lane = threadIdx.x & 63;
  int quad = lane >> 4, n16 = lane & 15;
  int qt = qtg * 4 + wv;          // this wave's q-tile
  int qb = qt * 32;

  // Q frags (bf16, pre-scaled by QSCALE)
  bf16x8 qf[2][2];
#pragma unroll
  for (int qc = 0; qc < 2; ++qc)
#pragma unroll
    for (int c = 0; c < 2; ++c)
      qf[qc][c] = *(const bf16x8*)&Qp[((size_t)h * NQ + qb + qc * 16 + n16) * 64 +
                                      c * 32 + quad * 8];

  f32x4 o[4][2];
#pragma unroll
  for (int dt = 0; dt < 4; ++dt)
#pragma unroll
    for (int qc = 0; qc < 2; ++qc) o[dt][qc] = (f32x4){0.f, 0.f, 0.f, 0.f};
  f32x4 o_l[2];
  o_l[0] = (f32x4){0.f, 0.f, 0.f, 0.f};
  o_l[1] = (f32x4){0.f, 0.f, 0.f, 0.f};

  f16x8 vones;
#pragma unroll
  for (int i = 0; i < 8; ++i) vones[i] = (_Float16)1.0f;

  const char* Kreg = (const char*)(Kp + (size_t)h * NK * 64 + (size_t)kp * 1024 * 64);
  const char* Vreg = (const char*)(Vf + ((size_t)h * 256 + kp * 32) * 2048);
  const unsigned* bT = bitsT + (size_t)(kp * 32) * NQ + qb;

  // per-lane source offsets: each wave stages 2 KB of the 8 KB tile image.
  const char* sb;
  int soff[2];
  if (wv < 2) {
    sb = Kreg;
#pragma unroll
    for (int i = 0; i < 2; ++i)
      soff[i] = ((wv * 16 + n16) * 64 + i * 32 + quad * 8) * 2;
  } else {
    sb = Vreg;
#pragma unroll
    for (int i = 0; i < 2; ++i)
      soff[i] = (wv - 2) * 2048 + i * 1024 + lane * 16;
  }

  auto stage = [&](int t, int bufidx) {
    char* d = &lds[bufidx][wv * 2048];
    const char* s0 = sb + (size_t)t * 4096;
#pragma unroll
    for (int i = 0; i < 2; ++i)
      gload16(s0 + soff[i], d + i * 1024);
  };

  auto compute = [&](int buf, unsigned wqa0, unsigned wqa1) {
    const char* Kl = lds[buf];
    const char* Vl = lds[buf] + 4096;

    bf16x8 kf[2][2];
#pragma unroll
    for (int kr = 0; kr < 2; ++kr)
#pragma unroll
      for (int c = 0; c < 2; ++c)
        kf[kr][c] = *(const bf16x8*)(Kl + (kr * 2 + c) * 1024 + lane * 16);

    // S^T = K·Q^T (bf16 K=32, pre-scaled)
    f32x4 s[2][2];
#pragma unroll
    for (int kr = 0; kr < 2; ++kr)
#pragma unroll
      for (int qc = 0; qc < 2; ++qc) {
        f32x4 acc = (f32x4){0.f, 0.f, 0.f, 0.f};
        acc = __builtin_amdgcn_mfma_f32_16x16x32_bf16(kf[kr][0], qf[qc][0], acc, 0, 0, 0);
        acc = __builtin_amdgcn_mfma_f32_16x16x32_bf16(kf[kr][1], qf[qc][1], acc, 0, 0, 0);
        s[kr][qc] = acc;
      }

    f16x8 vf8[4];
#pragma unroll
    for (int dt = 0; dt < 4; ++dt)
      vf8[dt] = *(const f16x8*)(Vl + dt * 1024 + lane * 16);

#pragma unroll
    for (int qc = 0; qc < 2; ++qc) {
      unsigned wq = (qc == 0 ? wqa0 : wqa1) >> (quad * 4);
      union { f16x8 v; f16x2 h[4]; } pu;
#pragma unroll
      for (int kr = 0; kr < 2; ++kr) {
        float e0 = __builtin_amdgcn_exp2f(s[kr][qc][0]);
        float e1 = __builtin_amdgcn_exp2f(s[kr][qc][1]);
        float e2 = __builtin_amdgcn_exp2f(s[kr][qc][2]);
        float e3 = __builtin_amdgcn_exp2f(s[kr][qc][3]);
        e0 = (wq & (1u << (kr * 16 + 0))) ? e0 : 0.f;
        e1 = (wq & (1u << (kr * 16 + 1))) ? e1 : 0.f;
        e2 = (wq & (1u << (kr * 16 + 2))) ? e2 : 0.f;
        e3 = (wq & (1u << (kr * 16 + 3))) ? e3 : 0.f;
        pu.h[kr * 2 + 0] = pkrtz(e0, e1);
        pu.h[kr * 2 + 1] = pkrtz(e2, e3);
      }
      // l-sum on the MFMA pipe: ones-A-frag, every reg = sum_k P[k][q]
      o_l[qc] = __builtin_amdgcn_mfma_f32_16x16x32_f16(vones, pu.v, o_l[qc], 0, 0, 0);
#pragma unroll
      for (int dt = 0; dt < 4; ++dt)
        o[dt][qc] = __builtin_amdgcn_mfma_f32_16x16x32_f16(vf8[dt], pu.v,
                                                           o[dt][qc], 0, 0, 0);
    }
  };

  // ---- prologue: bits(0), stage(0), stage(1); wait stage(0) only
  unsigned cw0 = bT[n16], cw1 = bT[16 + n16];
  stage(0, 0);
  stage(1, 1);
  asm volatile("s_waitcnt vmcnt(2)" ::: "memory");
  __builtin_amdgcn_sched_barrier(0);
  __builtin_amdgcn_s_barrier();

  // ---- main loop: 30 full-pipeline tiles (unroll 3 -> constant buf indices)
#pragma unroll 3
  for (int t = 0; t < 30; ++t) {
    stage(t + 2, (t + 2) % 3);
    unsigned nw0 = bT[(size_t)(t + 1) * NQ + n16];
    unsigned nw1 = bT[(size_t)(t + 1) * NQ + 16 + n16];
    compute(t % 3, cw0, cw1);
    cw0 = nw0; cw1 = nw1;
    asm volatile("s_waitcnt vmcnt(4)" ::: "memory");
    __builtin_amdgcn_sched_barrier(0);
    __builtin_amdgcn_s_barrier();
  }
  // t = 30: no stage; wait stage(31)
  {
    unsigned nw0 = bT[(size_t)31 * NQ + n16];
    unsigned nw1 = bT[(size_t)31 * NQ + 16 + n16];
    compute(0, cw0, cw1);
    cw0 = nw0; cw1 = nw1;
    asm volatile("s_waitcnt vmcnt(2)" ::: "memory");
    __builtin_amdgcn_sched_barrier(0);
    __builtin_amdgcn_s_barrier();
  }
  // t = 31: compute only
  compute(1, cw0, cw1);

  // ---- direct per-wave store (no cross-wave reduction needed)
  const size_t tile = ((size_t)h * NQT + qt) * NSUP + kp;
#pragma unroll
  for (int qc = 0; qc < 2; ++qc) {
#pragma unroll
    for (int dt = 0; dt < 4; ++dt) {
      union { f16x4 v; f16x2 h[2]; } u;
      u.h[0] = pkrtz(o[dt][qc][0], o[dt][qc][1]);
      u.h[1] = pkrtz(o[dt][qc][2], o[dt][qc][3]);
      *(f16x4*)&Opart[(tile * 32 + qc * 16 + n16) * 64 + dt * 16 + quad * 4] = u.v;
    }
    if (quad == 0) Lpart[tile * 32 + qc * 16 + n16] = o_l[qc][0];
  }
}

// ---------------------------------------------------------------------------
// 4. combine — EXACT round-6 version (part of the 294.1 best).
//    512 blocks x 8 rows; Opart read as f16x2 (paired a).
// ---------------------------------------------------------------------------
__global__ __launch_bounds__(256) void combine_kernel(
    const _Float16* __restrict__ Opart, const float* __restrict__ Lpart,
    const float* __restrict__ xQ, const float* __restrict__ Wg,
    const float* __restrict__ bg, const float* __restrict__ Wo,
    const float* __restrict__ bo, float* __restrict__ out) {
  __shared__ float comb[8][64];
  __shared__ float gred[32][8];
  __shared__ float glds[8][4];
  int nb = blockIdx.x;
  int tid = threadIdx.x;
  int row0 = nb * 8;

  // gates for this block's 8 rows x 4 heads (32 dots, 8-way split each)
  {
    int rh = tid >> 3, c = tid & 7;
    int r = rh >> 2, hh = rh & 3;
    const float* xp = xQ + (size_t)(row0 + r) * 256 + c * 32;
    const float* wp = Wg + hh * 256 + c * 32;
    float s = 0.f;
#pragma unroll
    for (int e = 0; e < 32; ++e) s = fmaf(xp[e], wp[e], s);
    gred[rh][c] = s;
  }
  __syncthreads();
  if (tid < 32) {
    float s = 0.f;
#pragma unroll
    for (int c = 0; c < 8; ++c) s += gred[tid][c];
    glds[tid >> 2][tid & 3] = 1.f / (1.f + __expf(-(s + bg[tid & 3])));
  }
  __syncthreads();

  int qt = nb >> 2, rbase = (nb & 3) * 8;
  {
    int athr = tid & 31, r = tid >> 5;      // 32 a-pairs x 8 rows
    int rl = rbase + r;
    int a0 = athr * 2;
    float c0 = 0.f, c1 = 0.f;
#pragma unroll
    for (int hh = 0; hh < NH; ++hh) {
      size_t t0 = ((size_t)hh * NQT + qt) * NSUP;
      float a0s = 0.f, a1s = 0.f, lt = 0.f;
#pragma unroll
      for (int s = 0; s < NSUP; ++s) {
        size_t t = t0 + s;
        f16x2 v = *(const f16x2*)&Opart[(t * 32 + rl) * 64 + a0];
        a0s += (float)v[0];
        a1s += (float)v[1];
        lt += Lpart[t * 32 + rl];
      }
      float g = glds[r][hh] / lt;
      c0 = fmaf(g, a0s, c0);
      c1 = fmaf(g, a1s, c1);
    }
    comb[r][a0] = c0;
    comb[r][a0 + 1] = c1;
  }
  __syncthreads();

  int j = tid;
  float accv[8];
#pragma unroll
  for (int r = 0; r < 8; ++r) accv[r] = bo[j];
  for (int aa = 0; aa < 64; ++aa) {
    float w = Wo[(size_t)aa * 256 + j];
#pragma unroll
    for (int r = 0; r < 8; ++r) accv[r] = fmaf(comb[r][aa], w, accv[r]);
  }
#pragma unroll
  for (int r = 0; r < 8; ++r)
    out[(size_t)(row0 + r) * 256 + j] = accv[r];
}

// ---------------------------------------------------------------------------
extern "C" void kernel_launch(void* const* d_in, const int* in_sizes, int n_in,
                              void* d_out, int out_size, void* d_ws, size_t ws_size,
                              hipStream_t stream) {
  const float* xQ  = (const float*)d_in[0];
  const float* xK  = (const float*)d_in[1];
  const int*   mask= (const int*)d_in[2];
  const float* Wq  = (const float*)d_in[3];
  const float* Wk  = (const float*)d_in[4];
  const float* Wv  = (const float*)d_in[5];
  const float* Wg  = (const float*)d_in[6];
  const float* bg  = (const float*)d_in[7];
  const float* Wo  = (const float*)d_in[8];
  const float* bo  = (const float*)d_in[9];
  float* out = (float*)d_out;

  char* ws = (char*)d_ws;
  unsigned short* Qp   = (unsigned short*)(ws + 0);         // 2 MB   [H][NQ][64]
  unsigned short* Kp   = (unsigned short*)(ws + 2097152);   // 4 MB   [H][NK][64]
  _Float16*       Vfp  = (_Float16*)(ws + 6291456);         // 4 MB   frag-linear
  unsigned*       bitsT= (unsigned*)(ws + 10485760);        // 4 MB   [word][row]
  float*          Lp   = (float*)(ws + 14680064);           // 512 KB (4096 tiles)
  _Float16*       Op   = (_Float16*)(ws + 15204352);        // 16.8 MB f16

  maskbits_kernel<<<dim3(8192), dim3(256), 0, stream>>>(mask, bitsT);
  proj_kernel<<<dim3(384), dim3(256), 0, stream>>>(xQ, xK, Wq, Wk, Wv, Qp, Kp, Vfp);
  attn_kernel<<<dim3(1024), dim3(256), 0, stream>>>(Qp, Kp, Vfp, bitsT, Op, Lp);
  combine_kernel<<<dim3(NQ / 8), dim3(256), 0, stream>>>(Op, Lp, xQ, Wg, bg,
                                                         Wo, bo, out);
}

// Round 12
// 295.686 us; speedup vs baseline: 1.0609x; 1.0131x over previous
//
#include <hip/hip_runtime.h>
#include <hip/hip_bf16.h>

#define NQ 4096
#define NK 8192
#define DQK 256
#define DA 64
#define NH 4
#define DOUT 256
#define NQT (NQ / 32)        // 128 q-tiles of 32
#define NSUP 8               // surviving partials per (h,qt): 8 key-regions
#define LOG2E 1.44269504088896340736f
#define QSCALE (0.125f * LOG2E)   // 1/sqrt(64) * log2(e), folded into Qp

typedef __attribute__((ext_vector_type(8))) short bf16x8;
typedef __attribute__((ext_vector_type(4))) float f32x4;
typedef __attribute__((ext_vector_type(2))) _Float16 f16x2;
typedef __attribute__((ext_vector_type(4))) _Float16 f16x4;
typedef __attribute__((ext_vector_type(8))) _Float16 f16x8;

__device__ inline unsigned short f2bf(float f) {
  union { float f; unsigned u; } v; v.f = f;
  unsigned r = v.u + 0x7fff + ((v.u >> 16) & 1);  // RNE
  return (unsigned short)(r >> 16);
}

__device__ inline f16x2 pkrtz(float a, float b) {
  return __builtin_bit_cast(f16x2, __builtin_amdgcn_cvt_pkrtz(a, b));
}

__device__ inline void gload16(const void* g, void* l) {
  __builtin_amdgcn_global_load_lds(
      (const __attribute__((address_space(1))) void*)g,
      (__attribute__((address_space(3))) void*)l, 16, 0, 0);
}

// ---------------------------------------------------------------------------
// 1. mask (int32 NQ x NK) -> TRANSPOSED bitmask bitsT[word32][row] (4 MB).
// ---------------------------------------------------------------------------
__global__ __launch_bounds__(256) void maskbits_kernel(
    const int* __restrict__ mask, unsigned* __restrict__ bitsT) {
  const int NW = 8192 * 4;                       // total waves
  int wid = blockIdx.x * 4 + (threadIdx.x >> 6);
  int lane = threadIdx.x & 63;
  for (int j = 0; j < 2; ++j) {
    int v[8];
#pragma unroll
    for (int u = 0; u < 8; ++u) {
      int c = wid + (j * 8 + u) * NW;   // u64 chunk id: row = c>>7, ch = c&127
      v[u] = mask[(size_t)(c >> 7) * NK + (c & 127) * 64 + lane];
    }
#pragma unroll
    for (int u = 0; u < 8; ++u) {
      unsigned long long b = __ballot(v[u] != 0);
      int c = wid + (j * 8 + u) * NW;
      int n = c >> 7, ch = c & 127;
      if (lane == 0)  bitsT[(size_t)(2 * ch) * NQ + n] = (unsigned)b;
      if (lane == 32) bitsT[(size_t)(2 * ch + 1) * NQ + n] = (unsigned)(b >> 32);
    }
  }
}

// ---------------------------------------------------------------------------
// 2. projections — EXACT round-6 version (640 blocks, 3-way split).
// ---------------------------------------------------------------------------
__global__ __launch_bounds__(256) void proj_kernel(
    const float* __restrict__ xQ, const float* __restrict__ xK,
    const float* __restrict__ Wq, const float* __restrict__ Wk,
    const float* __restrict__ Wv,
    unsigned short* __restrict__ Qp, unsigned short* __restrict__ Kp,
    _Float16* __restrict__ Vf) {
  __shared__ __align__(16) unsigned short Wt[64][264];  // Wt[d][c], padded

  int b = blockIdx.x;
  int proj, h, rb;
  if (b < 128)       { proj = 0; h = b >> 5;  rb = b & 31; }
  else if (b < 384)  { proj = 1; b -= 128; h = b >> 6; rb = b & 63; }
  else               { proj = 2; b -= 384; h = b >> 6; rb = b & 63; }
  const float* x = (proj == 0) ? xQ : xK;
  const float* W = (proj == 0 ? Wq : (proj == 1 ? Wk : Wv)) + (size_t)h * 256 * 64;

  for (int i = threadIdx.x; i < 16384; i += 256)
    Wt[i & 63][i >> 6] = f2bf(W[i]);
  __syncthreads();

  int lane = threadIdx.x & 63, wv = threadIdx.x >> 6;
  int quad = lane >> 4, n16 = lane & 15;
  int r0 = rb * 128 + wv * 32;          // 32 rows per wave

  f32x4 acc[2][4];
#pragma unroll
  for (int mt = 0; mt < 2; ++mt)
#pragma unroll
    for (int nt = 0; nt < 4; ++nt)
      acc[mt][nt] = (f32x4){0.f, 0.f, 0.f, 0.f};

#pragma unroll
  for (int it = 0; it < 8; ++it) {
    const int k0 = it * 32;
    bf16x8 af[2];
#pragma unroll
    for (int mt = 0; mt < 2; ++mt) {
      const float* xp = x + (size_t)(r0 + mt * 16 + n16) * 256 + k0 + quad * 8;
      const float4 a0 = *(const float4*)xp;
      const float4 a1 = *(const float4*)(xp + 4);
      bf16x8 a;
      a[0] = (short)f2bf(a0.x); a[1] = (short)f2bf(a0.y);
      a[2] = (short)f2bf(a0.z); a[3] = (short)f2bf(a0.w);
      a[4] = (short)f2bf(a1.x); a[5] = (short)f2bf(a1.y);
      a[6] = (short)f2bf(a1.z); a[7] = (short)f2bf(a1.w);
      af[mt] = a;
    }
    bf16x8 bfr[4];
#pragma unroll
    for (int nt = 0; nt < 4; ++nt)
      bfr[nt] = *(const bf16x8*)&Wt[nt * 16 + n16][k0 + quad * 8];
#pragma unroll
    for (int mt = 0; mt < 2; ++mt)
#pragma unroll
      for (int nt = 0; nt < 4; ++nt)
        acc[mt][nt] = __builtin_amdgcn_mfma_f32_16x16x32_bf16(
            af[mt], bfr[nt], acc[mt][nt], 0, 0, 0);
  }

  if (proj < 2) {
    unsigned short* outp =
        (proj == 0 ? Qp : Kp) + (size_t)h * (size_t)(proj == 0 ? NQ : NK) * 64;
    const float sc = (proj == 0) ? QSCALE : 1.0f;
#pragma unroll
    for (int mt = 0; mt < 2; ++mt)
#pragma unroll
      for (int nt = 0; nt < 4; ++nt)
#pragma unroll
        for (int r = 0; r < 4; ++r) {
          int row = r0 + mt * 16 + quad * 4 + r;
          int col = nt * 16 + n16;
          outp[(size_t)row * 64 + col] = f2bf(acc[mt][nt][r] * sc);
        }
  } else {
    // K=32 fragment-linear V: tile = h*256 + keyblock32
    int tile = h * 256 + (r0 >> 5);
#pragma unroll
    for (int nt = 0; nt < 4; ++nt) {
      f16x8 pk;
      pk[0] = (_Float16)acc[0][nt][0]; pk[1] = (_Float16)acc[0][nt][1];
      pk[2] = (_Float16)acc[0][nt][2]; pk[3] = (_Float16)acc[0][nt][3];
      pk[4] = (_Float16)acc[1][nt][0]; pk[5] = (_Float16)acc[1][nt][1];
      pk[6] = (_Float16)acc[1][nt][2]; pk[7] = (_Float16)acc[1][nt][3];
      *(f16x8*)&Vf[(((size_t)tile * 4 + nt) * 64 + lane) * 8] = pk;
    }
  }
}

// ---------------------------------------------------------------------------
// 3. flash attention — r6 structure with the depth-1 defect fixed:
//    bits loads issued BEFORE stage() each iteration (pinned by
//    sched_barrier), so compute(t)'s auto-wait for bits(t) (oldest in the
//    vm queue) no longer drains stage(t+1). Counted waits re-derived by
//    FIFO instruction position (stage = 2 instr, bits = 2 instr):
//      steady:  end-of-iter vmcnt(4) = drain stage(t+1) exactly,
//               leave bits(t+1)+stage(t+2) in flight  -> true depth-2.
//      prologue vmcnt(2); epilogue vmcnt(2).
// ---------------------------------------------------------------------------
__global__ __launch_bounds__(256, 4) void attn_kernel(
    const unsigned short* __restrict__ Qp, const unsigned short* __restrict__ Kp,
    const _Float16* __restrict__ Vf, const unsigned* __restrict__ bitsT,
    _Float16* __restrict__ Opart, float* __restrict__ Lpart) {
  __shared__ __align__(16) char lds[3][8192];   // [buf][K 4KB | V 4KB]

  // bijective XCD swizzle (8 XCDs, 1024 blocks, 128/chunk)
  int orig = blockIdx.x;
  int wgid = (orig & 7) * 128 + (orig >> 3);
  int qtg = wgid & 31;
  int combo = wgid >> 5;          // h*8 + kp: each XCD owns 4 combos, same h
  int kp = combo & 7, h = combo >> 3;

  int wv = threadIdx.x >> 6, lane = threadIdx.x & 63;
  int quad = lane >> 4, n16 = lane & 15;
  int qt = qtg * 4 + wv;          // this wave's q-tile
  int qb = qt * 32;

  // Q frags (bf16, pre-scaled by QSCALE)
  bf16x8 qf[2][2];
#pragma unroll
  for (int qc = 0; qc < 2; ++qc)
#pragma unroll
    for (int c = 0; c < 2; ++c)
      qf[qc][c] = *(const bf16x8*)&Qp[((size_t)h * NQ + qb + qc * 16 + n16) * 64 +
                                      c * 32 + quad * 8];

  f32x4 o[4][2];
#pragma unroll
  for (int dt = 0; dt < 4; ++dt)
#pragma unroll
    for (int qc = 0; qc < 2; ++qc) o[dt][qc] = (f32x4){0.f, 0.f, 0.f, 0.f};
  f32x4 o_l[2];
  o_l[0] = (f32x4){0.f, 0.f, 0.f, 0.f};
  o_l[1] = (f32x4){0.f, 0.f, 0.f, 0.f};

  f16x8 vones;
#pragma unroll
  for (int i = 0; i < 8; ++i) vones[i] = (_Float16)1.0f;

  const char* Kreg = (const char*)(Kp + (size_t)h * NK * 64 + (size_t)kp * 1024 * 64);
  const char* Vreg = (const char*)(Vf + ((size_t)h * 256 + kp * 32) * 2048);
  const unsigned* bT = bitsT + (size_t)(kp * 32) * NQ + qb;

  // per-lane source offsets: each wave stages 2 KB of the 8 KB tile image.
  const char* sb;
  int soff[2];
  if (wv < 2) {
    sb = Kreg;
#pragma unroll
    for (int i = 0; i < 2; ++i)
      soff[i] = ((wv * 16 + n16) * 64 + i * 32 + quad * 8) * 2;
  } else {
    sb = Vreg;
#pragma unroll
    for (int i = 0; i < 2; ++i)
      soff[i] = (wv - 2) * 2048 + i * 1024 + lane * 16;
  }

  auto stage = [&](int t, int bufidx) {
    char* d = &lds[bufidx][wv * 2048];
    const char* s0 = sb + (size_t)t * 4096;
#pragma unroll
    for (int i = 0; i < 2; ++i)
      gload16(s0 + soff[i], d + i * 1024);
  };

  auto compute = [&](int buf, unsigned wqa0, unsigned wqa1) {
    const char* Kl = lds[buf];
    const char* Vl = lds[buf] + 4096;

    bf16x8 kf[2][2];
#pragma unroll
    for (int kr = 0; kr < 2; ++kr)
#pragma unroll
      for (int c = 0; c < 2; ++c)
        kf[kr][c] = *(const bf16x8*)(Kl + (kr * 2 + c) * 1024 + lane * 16);

    // S^T = K·Q^T (bf16 K=32, pre-scaled)
    f32x4 s[2][2];
#pragma unroll
    for (int kr = 0; kr < 2; ++kr)
#pragma unroll
      for (int qc = 0; qc < 2; ++qc) {
        f32x4 acc = (f32x4){0.f, 0.f, 0.f, 0.f};
        acc = __builtin_amdgcn_mfma_f32_16x16x32_bf16(kf[kr][0], qf[qc][0], acc, 0, 0, 0);
        acc = __builtin_amdgcn_mfma_f32_16x16x32_bf16(kf[kr][1], qf[qc][1], acc, 0, 0, 0);
        s[kr][qc] = acc;
      }

    f16x8 vf8[4];
#pragma unroll
    for (int dt = 0; dt < 4; ++dt)
      vf8[dt] = *(const f16x8*)(Vl + dt * 1024 + lane * 16);

#pragma unroll
    for (int qc = 0; qc < 2; ++qc) {
      unsigned wq = (qc == 0 ? wqa0 : wqa1) >> (quad * 4);
      union { f16x8 v; f16x2 h[4]; } pu;
#pragma unroll
      for (int kr = 0; kr < 2; ++kr) {
        float e0 = __builtin_amdgcn_exp2f(s[kr][qc][0]);
        float e1 = __builtin_amdgcn_exp2f(s[kr][qc][1]);
        float e2 = __builtin_amdgcn_exp2f(s[kr][qc][2]);
        float e3 = __builtin_amdgcn_exp2f(s[kr][qc][3]);
        e0 = (wq & (1u << (kr * 16 + 0))) ? e0 : 0.f;
        e1 = (wq & (1u << (kr * 16 + 1))) ? e1 : 0.f;
        e2 = (wq & (1u << (kr * 16 + 2))) ? e2 : 0.f;
        e3 = (wq & (1u << (kr * 16 + 3))) ? e3 : 0.f;
        pu.h[kr * 2 + 0] = pkrtz(e0, e1);
        pu.h[kr * 2 + 1] = pkrtz(e2, e3);
      }
      // l-sum on the MFMA pipe: ones-A-frag, every reg = sum_k P[k][q]
      o_l[qc] = __builtin_amdgcn_mfma_f32_16x16x32_f16(vones, pu.v, o_l[qc], 0, 0, 0);
#pragma unroll
      for (int dt = 0; dt < 4; ++dt)
        o[dt][qc] = __builtin_amdgcn_mfma_f32_16x16x32_f16(vf8[dt], pu.v,
                                                           o[dt][qc], 0, 0, 0);
    }
  };

  // ---- prologue: bits(0) FIRST, then stage(0), stage(1).
  // queue: [bits0(2), stage0(2), stage1(2)] -> vmcnt(2) drains bits0+stage0.
  unsigned cw0 = bT[n16], cw1 = bT[16 + n16];
  __builtin_amdgcn_sched_barrier(0);
  stage(0, 0);
  stage(1, 1);
  asm volatile("s_waitcnt vmcnt(2)" ::: "memory");
  __builtin_amdgcn_sched_barrier(0);
  __builtin_amdgcn_s_barrier();

  // ---- main loop: bits(t+1) issued BEFORE stage(t+2); end-of-iter vmcnt(4)
  // drains exactly stage(t+1) (leaves bits(t+1)+stage(t+2) in flight).
#pragma unroll 3
  for (int t = 0; t < 30; ++t) {
    unsigned nw0 = bT[(size_t)(t + 1) * NQ + n16];
    unsigned nw1 = bT[(size_t)(t + 1) * NQ + 16 + n16];
    __builtin_amdgcn_sched_barrier(0);   // pin bits before stage in vm order
    stage(t + 2, (t + 2) % 3);
    compute(t % 3, cw0, cw1);
    cw0 = nw0; cw1 = nw1;
    asm volatile("s_waitcnt vmcnt(4)" ::: "memory");
    __builtin_amdgcn_sched_barrier(0);
    __builtin_amdgcn_s_barrier();
  }
  // t = 30: bits(31), no stage; drain stage(31) (leave bits(31))
  {
    unsigned nw0 = bT[(size_t)31 * NQ + n16];
    unsigned nw1 = bT[(size_t)31 * NQ + 16 + n16];
    __builtin_amdgcn_sched_barrier(0);
    compute(0, cw0, cw1);
    cw0 = nw0; cw1 = nw1;
    asm volatile("s_waitcnt vmcnt(2)" ::: "memory");
    __builtin_amdgcn_sched_barrier(0);
    __builtin_amdgcn_s_barrier();
  }
  // t = 31: compute only
  compute(1, cw0, cw1);

  // ---- direct per-wave store (no cross-wave reduction needed)
  const size_t tile = ((size_t)h * NQT + qt) * NSUP + kp;
#pragma unroll
  for (int qc = 0; qc < 2; ++qc) {
#pragma unroll
    for (int dt = 0; dt < 4; ++dt) {
      union { f16x4 v; f16x2 h[2]; } u;
      u.h[0] = pkrtz(o[dt][qc][0], o[dt][qc][1]);
      u.h[1] = pkrtz(o[dt][qc][2], o[dt][qc][3]);
      *(f16x4*)&Opart[(tile * 32 + qc * 16 + n16) * 64 + dt * 16 + quad * 4] = u.v;
    }
    if (quad == 0) Lpart[tile * 32 + qc * 16 + n16] = o_l[qc][0];
  }
}

// ---------------------------------------------------------------------------
// 4. combine — EXACT round-6 version (part of the 294.1 best).
//    512 blocks x 8 rows; Opart read as f16x2 (paired a).
// ---------------------------------------------------------------------------
__global__ __launch_bounds__(256) void combine_kernel(
    const _Float16* __restrict__ Opart, const float* __restrict__ Lpart,
    const float* __restrict__ xQ, const float* __restrict__ Wg,
    const float* __restrict__ bg, const float* __restrict__ Wo,
    const float* __restrict__ bo, float* __restrict__ out) {
  __shared__ float comb[8][64];
  __shared__ float gred[32][8];
  __shared__ float glds[8][4];
  int nb = blockIdx.x;
  int tid = threadIdx.x;
  int row0 = nb * 8;

  // gates for this block's 8 rows x 4 heads (32 dots, 8-way split each)
  {
    int rh = tid >> 3, c = tid & 7;
    int r = rh >> 2, hh = rh & 3;
    const float* xp = xQ + (size_t)(row0 + r) * 256 + c * 32;
    const float* wp = Wg + hh * 256 + c * 32;
    float s = 0.f;
#pragma unroll
    for (int e = 0; e < 32; ++e) s = fmaf(xp[e], wp[e], s);
    gred[rh][c] = s;
  }
  __syncthreads();
  if (tid < 32) {
    float s = 0.f;
#pragma unroll
    for (int c = 0; c < 8; ++c) s += gred[tid][c];
    glds[tid >> 2][tid & 3] = 1.f / (1.f + __expf(-(s + bg[tid & 3])));
  }
  __syncthreads();

  int qt = nb >> 2, rbase = (nb & 3) * 8;
  {
    int athr = tid & 31, r = tid >> 5;      // 32 a-pairs x 8 rows
    int rl = rbase + r;
    int a0 = athr * 2;
    float c0 = 0.f, c1 = 0.f;
#pragma unroll
    for (int hh = 0; hh < NH; ++hh) {
      size_t t0 = ((size_t)hh * NQT + qt) * NSUP;
      float a0s = 0.f, a1s = 0.f, lt = 0.f;
#pragma unroll
      for (int s = 0; s < NSUP; ++s) {
        size_t t = t0 + s;
        f16x2 v = *(const f16x2*)&Opart[(t * 32 + rl) * 64 + a0];
        a0s += (float)v[0];
        a1s += (float)v[1];
        lt += Lpart[t * 32 + rl];
      }
      float g = glds[r][hh] / lt;
      c0 = fmaf(g, a0s, c0);
      c1 = fmaf(g, a1s, c1);
    }
    comb[r][a0] = c0;
    comb[r][a0 + 1] = c1;
  }
  __syncthreads();

  int j = tid;
  float accv[8];
#pragma unroll
  for (int r = 0; r < 8; ++r) accv[r] = bo[j];
  for (int aa = 0; aa < 64; ++aa) {
    float w = Wo[(size_t)aa * 256 + j];
#pragma unroll
    for (int r = 0; r < 8; ++r) accv[r] = fmaf(comb[r][aa], w, accv[r]);
  }
#pragma unroll
  for (int r = 0; r < 8; ++r)
    out[(size_t)(row0 + r) * 256 + j] = accv[r];
}

// ---------------------------------------------------------------------------
extern "C" void kernel_launch(void* const* d_in, const int* in_sizes, int n_in,
                              void* d_out, int out_size, void* d_ws, size_t ws_size,
                              hipStream_t stream) {
  const float* xQ  = (const float*)d_in[0];
  const float* xK  = (const float*)d_in[1];
  const int*   mask= (const int*)d_in[2];
  const float* Wq  = (const float*)d_in[3];
  const float* Wk  = (const float*)d_in[4];
  const float* Wv  = (const float*)d_in[5];
  const float* Wg  = (const float*)d_in[6];
  const float* bg  = (const float*)d_in[7];
  const float* Wo  = (const float*)d_in[8];
  const float* bo  = (const float*)d_in[9];
  float* out = (float*)d_out;

  char* ws = (char*)d_ws;
  unsigned short* Qp   = (unsigned short*)(ws + 0);         // 2 MB   [H][NQ][64]
  unsigned short* Kp   = (unsigned short*)(ws + 2097152);   // 4 MB   [H][NK][64]
  _Float16*       Vfp  = (_Float16*)(ws + 6291456);         // 4 MB   frag-linear
  unsigned*       bitsT= (unsigned*)(ws + 10485760);        // 4 MB   [word][row]
  float*          Lp   = (float*)(ws + 14680064);           // 512 KB (4096 tiles)
  _Float16*       Op   = (_Float16*)(ws + 15204352);        // 16.8 MB f16

  maskbits_kernel<<<dim3(8192), dim3(256), 0, stream>>>(mask, bitsT);
  proj_kernel<<<dim3(640), dim3(256), 0, stream>>>(xQ, xK, Wq, Wk, Wv, Qp, Kp, Vfp);
  attn_kernel<<<dim3(1024), dim3(256), 0, stream>>>(Qp, Kp, Vfp, bitsT, Op, Lp);
  combine_kernel<<<dim3(NQ / 8), dim3(256), 0, stream>>>(Op, Lp, xQ, Wg, bg,
                                                         Wo, bo, out);
}

// Round 13
// 290.878 us; speedup vs baseline: 1.0784x; 1.0165x over previous
//
#include <hip/hip_runtime.h>
#include <hip/hip_bf16.h>

#define NQ 4096
#define NK 8192
#define DQK 256
#define DA 64
#define NH 4
#define DOUT 256
#define NQT (NQ / 32)        // 128 q-tiles of 32
#define NSUP 8               // surviving partials per (h,qt): 8 key-regions
#define LOG2E 1.44269504088896340736f
#define QSCALE (0.125f * LOG2E)   // 1/sqrt(64) * log2(e), folded into Qp

typedef __attribute__((ext_vector_type(8))) short bf16x8;
typedef __attribute__((ext_vector_type(4))) float f32x4;
typedef __attribute__((ext_vector_type(2))) _Float16 f16x2;
typedef __attribute__((ext_vector_type(4))) _Float16 f16x4;
typedef __attribute__((ext_vector_type(8))) _Float16 f16x8;

__device__ inline unsigned short f2bf(float f) {
  union { float f; unsigned u; } v; v.f = f;
  unsigned r = v.u + 0x7fff + ((v.u >> 16) & 1);  // RNE
  return (unsigned short)(r >> 16);
}

__device__ inline f16x2 pkrtz(float a, float b) {
  return __builtin_bit_cast(f16x2, __builtin_amdgcn_cvt_pkrtz(a, b));
}

__device__ inline void gload16(const void* g, void* l) {
  __builtin_amdgcn_global_load_lds(
      (const __attribute__((address_space(1))) void*)g,
      (__attribute__((address_space(3))) void*)l, 16, 0, 0);
}

// ---------------------------------------------------------------------------
// 1. FUSED: blocks 0..47 convert Wq/Wk/Wv (f32) -> Wf, a global bf16 image in
//    EXACT MFMA B-fragment order (16B per (it,nt,lane) frag; 384 KB total,
//    L2-resident). Blocks 48.. do the mask->bitmask transpose. The converter
//    runs once (196K elements) instead of once per proj block (10.5M), and
//    removes proj's 8-way-conflicted LDS fill + barrier entirely.
//    Neither path uses LDS -> no r8-style occupancy poisoning.
// ---------------------------------------------------------------------------
__global__ __launch_bounds__(256) void maskbits_kernel(
    const int* __restrict__ mask, unsigned* __restrict__ bitsT,
    const float* __restrict__ Wq, const float* __restrict__ Wk,
    const float* __restrict__ Wv, unsigned short* __restrict__ Wf) {
  int b = blockIdx.x;
  if (b < 48) {
    // ---- W fragment-image converter: 4 blocks per (proj,head) ----
    int p4h = b >> 2;                    // proj*4 + h, 0..11
    int p = p4h >> 2, h = p4h & 3;
    const float* W = (p == 0 ? Wq : (p == 1 ? Wk : Wv)) + (size_t)h * 16384;
    unsigned short* dst = Wf + (size_t)p4h * 16384;
    int q = b & 3, tid = threadIdx.x;
    for (int s = q * 512 + tid; s < (q + 1) * 512; s += 256) {
      int it = s >> 8, rem = s & 255, nt = rem >> 6, lane = rem & 63;
      int k0 = it * 32 + (lane >> 4) * 8;
      int c = nt * 16 + (lane & 15);
      unsigned short tmp[8];
#pragma unroll
      for (int j = 0; j < 8; ++j) tmp[j] = f2bf(W[(size_t)(k0 + j) * 64 + c]);
      *(bf16x8*)&dst[(size_t)s * 8] = *(const bf16x8*)tmp;
    }
    return;
  }
  b -= 48;

  const int NW = 8192 * 4;                       // total waves
  int wid = b * 4 + (threadIdx.x >> 6);
  int lane = threadIdx.x & 63;
  for (int j = 0; j < 2; ++j) {
    int v[8];
#pragma unroll
    for (int u = 0; u < 8; ++u) {
      int c = wid + (j * 8 + u) * NW;   // u64 chunk id: row = c>>7, ch = c&127
      v[u] = mask[(size_t)(c >> 7) * NK + (c & 127) * 64 + lane];
    }
#pragma unroll
    for (int u = 0; u < 8; ++u) {
      unsigned long long bb = __ballot(v[u] != 0);
      int c = wid + (j * 8 + u) * NW;
      int n = c >> 7, ch = c & 127;
      if (lane == 0)  bitsT[(size_t)(2 * ch) * NQ + n] = (unsigned)bb;
      if (lane == 32) bitsT[(size_t)(2 * ch + 1) * NQ + n] = (unsigned)(bb >> 32);
    }
  }
}

// ---------------------------------------------------------------------------
// 2. projections, LDS-FREE: B-frags load directly from the pre-converted
//    fragment image (16B coalesced; same addr across the 4 waves -> L1).
//    No conversions of W, no LDS, no __syncthreads.
// ---------------------------------------------------------------------------
__global__ __launch_bounds__(256) void proj_kernel(
    const float* __restrict__ xQ, const float* __restrict__ xK,
    const unsigned short* __restrict__ Wf,
    unsigned short* __restrict__ Qp, unsigned short* __restrict__ Kp,
    _Float16* __restrict__ Vf) {
  int b = blockIdx.x;
  int proj, h, rb;
  if (b < 128)       { proj = 0; h = b >> 5;  rb = b & 31; }
  else if (b < 384)  { proj = 1; b -= 128; h = b >> 6; rb = b & 63; }
  else               { proj = 2; b -= 384; h = b >> 6; rb = b & 63; }
  const float* x = (proj == 0) ? xQ : xK;
  const unsigned short* Wfh = Wf + (size_t)(proj * 4 + h) * 16384;

  int lane = threadIdx.x & 63, wv = threadIdx.x >> 6;
  int quad = lane >> 4, n16 = lane & 15;
  int r0 = rb * 128 + wv * 32;          // 32 rows per wave

  f32x4 acc[2][4];
#pragma unroll
  for (int mt = 0; mt < 2; ++mt)
#pragma unroll
    for (int nt = 0; nt < 4; ++nt)
      acc[mt][nt] = (f32x4){0.f, 0.f, 0.f, 0.f};

#pragma unroll
  for (int it = 0; it < 8; ++it) {
    const int k0 = it * 32;
    bf16x8 af[2];
#pragma unroll
    for (int mt = 0; mt < 2; ++mt) {
      const float* xp = x + (size_t)(r0 + mt * 16 + n16) * 256 + k0 + quad * 8;
      const float4 a0 = *(const float4*)xp;
      const float4 a1 = *(const float4*)(xp + 4);
      bf16x8 a;
      a[0] = (short)f2bf(a0.x); a[1] = (short)f2bf(a0.y);
      a[2] = (short)f2bf(a0.z); a[3] = (short)f2bf(a0.w);
      a[4] = (short)f2bf(a1.x); a[5] = (short)f2bf(a1.y);
      a[6] = (short)f2bf(a1.z); a[7] = (short)f2bf(a1.w);
      af[mt] = a;
    }
    bf16x8 bfr[4];
#pragma unroll
    for (int nt = 0; nt < 4; ++nt)
      bfr[nt] = *(const bf16x8*)&Wfh[((size_t)(it * 4 + nt) * 64 + lane) * 8];
#pragma unroll
    for (int mt = 0; mt < 2; ++mt)
#pragma unroll
      for (int nt = 0; nt < 4; ++nt)
        acc[mt][nt] = __builtin_amdgcn_mfma_f32_16x16x32_bf16(
            af[mt], bfr[nt], acc[mt][nt], 0, 0, 0);
  }

  if (proj < 2) {
    unsigned short* outp =
        (proj == 0 ? Qp : Kp) + (size_t)h * (size_t)(proj == 0 ? NQ : NK) * 64;
    const float sc = (proj == 0) ? QSCALE : 1.0f;
#pragma unroll
    for (int mt = 0; mt < 2; ++mt)
#pragma unroll
      for (int nt = 0; nt < 4; ++nt)
#pragma unroll
        for (int r = 0; r < 4; ++r) {
          int row = r0 + mt * 16 + quad * 4 + r;
          int col = nt * 16 + n16;
          outp[(size_t)row * 64 + col] = f2bf(acc[mt][nt][r] * sc);
        }
  } else {
    // K=32 fragment-linear V: tile = h*256 + keyblock32
    int tile = h * 256 + (r0 >> 5);
#pragma unroll
    for (int nt = 0; nt < 4; ++nt) {
      f16x8 pk;
      pk[0] = (_Float16)acc[0][nt][0]; pk[1] = (_Float16)acc[0][nt][1];
      pk[2] = (_Float16)acc[0][nt][2]; pk[3] = (_Float16)acc[0][nt][3];
      pk[4] = (_Float16)acc[1][nt][0]; pk[5] = (_Float16)acc[1][nt][1];
      pk[6] = (_Float16)acc[1][nt][2]; pk[7] = (_Float16)acc[1][nt][3];
      *(f16x8*)&Vf[(((size_t)tile * 4 + nt) * 64 + lane) * 8] = pk;
    }
  }
}

// ---------------------------------------------------------------------------
// 3. flash attention — round-12 version (ties best measured).
// ---------------------------------------------------------------------------
__global__ __launch_bounds__(256, 4) void attn_kernel(
    const unsigned short* __restrict__ Qp, const unsigned short* __restrict__ Kp,
    const _Float16* __restrict__ Vf, const unsigned* __restrict__ bitsT,
    _Float16* __restrict__ Opart, float* __restrict__ Lpart) {
  __shared__ __align__(16) char lds[3][8192];   // [buf][K 4KB | V 4KB]

  // bijective XCD swizzle (8 XCDs, 1024 blocks, 128/chunk)
  int orig = blockIdx.x;
  int wgid = (orig & 7) * 128 + (orig >> 3);
  int qtg = wgid & 31;
  int combo = wgid >> 5;          // h*8 + kp: each XCD owns 4 combos, same h
  int kp = combo & 7, h = combo >> 3;

  int wv = threadIdx.x >> 6, lane = threadIdx.x & 63;
  int quad = lane >> 4, n16 = lane & 15;
  int qt = qtg * 4 + wv;          // this wave's q-tile
  int qb = qt * 32;

  // Q frags (bf16, pre-scaled by QSCALE)
  bf16x8 qf[2][2];
#pragma unroll
  for (int qc = 0; qc < 2; ++qc)
#pragma unroll
    for (int c = 0; c < 2; ++c)
      qf[qc][c] = *(const bf16x8*)&Qp[((size_t)h * NQ + qb + qc * 16 + n16) * 64 +
                                      c * 32 + quad * 8];

  f32x4 o[4][2];
#pragma unroll
  for (int dt = 0; dt < 4; ++dt)
#pragma unroll
    for (int qc = 0; qc < 2; ++qc) o[dt][qc] = (f32x4){0.f, 0.f, 0.f, 0.f};
  f32x4 o_l[2];
  o_l[0] = (f32x4){0.f, 0.f, 0.f, 0.f};
  o_l[1] = (f32x4){0.f, 0.f, 0.f, 0.f};

  f16x8 vones;
#pragma unroll
  for (int i = 0; i < 8; ++i) vones[i] = (_Float16)1.0f;

  const char* Kreg = (const char*)(Kp + (size_t)h * NK * 64 + (size_t)kp * 1024 * 64);
  const char* Vreg = (const char*)(Vf + ((size_t)h * 256 + kp * 32) * 2048);
  const unsigned* bT = bitsT + (size_t)(kp * 32) * NQ + qb;

  // per-lane source offsets: each wave stages 2 KB of the 8 KB tile image.
  const char* sb;
  int soff[2];
  if (wv < 2) {
    sb = Kreg;
#pragma unroll
    for (int i = 0; i < 2; ++i)
      soff[i] = ((wv * 16 + n16) * 64 + i * 32 + quad * 8) * 2;
  } else {
    sb = Vreg;
#pragma unroll
    for (int i = 0; i < 2; ++i)
      soff[i] = (wv - 2) * 2048 + i * 1024 + lane * 16;
  }

  auto stage = [&](int t, int bufidx) {
    char* d = &lds[bufidx][wv * 2048];
    const char* s0 = sb + (size_t)t * 4096;
#pragma unroll
    for (int i = 0; i < 2; ++i)
      gload16(s0 + soff[i], d + i * 1024);
  };

  auto compute = [&](int buf, unsigned wqa0, unsigned wqa1) {
    const char* Kl = lds[buf];
    const char* Vl = lds[buf] + 4096;

    bf16x8 kf[2][2];
#pragma unroll
    for (int kr = 0; kr < 2; ++kr)
#pragma unroll
      for (int c = 0; c < 2; ++c)
        kf[kr][c] = *(const bf16x8*)(Kl + (kr * 2 + c) * 1024 + lane * 16);

    // S^T = K·Q^T (bf16 K=32, pre-scaled)
    f32x4 s[2][2];
#pragma unroll
    for (int kr = 0; kr < 2; ++kr)
#pragma unroll
      for (int qc = 0; qc < 2; ++qc) {
        f32x4 acc = (f32x4){0.f, 0.f, 0.f, 0.f};
        acc = __builtin_amdgcn_mfma_f32_16x16x32_bf16(kf[kr][0], qf[qc][0], acc, 0, 0, 0);
        acc = __builtin_amdgcn_mfma_f32_16x16x32_bf16(kf[kr][1], qf[qc][1], acc, 0, 0, 0);
        s[kr][qc] = acc;
      }

    f16x8 vf8[4];
#pragma unroll
    for (int dt = 0; dt < 4; ++dt)
      vf8[dt] = *(const f16x8*)(Vl + dt * 1024 + lane * 16);

#pragma unroll
    for (int qc = 0; qc < 2; ++qc) {
      unsigned wq = (qc == 0 ? wqa0 : wqa1) >> (quad * 4);
      union { f16x8 v; f16x2 h[4]; } pu;
#pragma unroll
      for (int kr = 0; kr < 2; ++kr) {
        float e0 = __builtin_amdgcn_exp2f(s[kr][qc][0]);
        float e1 = __builtin_amdgcn_exp2f(s[kr][qc][1]);
        float e2 = __builtin_amdgcn_exp2f(s[kr][qc][2]);
        float e3 = __builtin_amdgcn_exp2f(s[kr][qc][3]);
        e0 = (wq & (1u << (kr * 16 + 0))) ? e0 : 0.f;
        e1 = (wq & (1u << (kr * 16 + 1))) ? e1 : 0.f;
        e2 = (wq & (1u << (kr * 16 + 2))) ? e2 : 0.f;
        e3 = (wq & (1u << (kr * 16 + 3))) ? e3 : 0.f;
        pu.h[kr * 2 + 0] = pkrtz(e0, e1);
        pu.h[kr * 2 + 1] = pkrtz(e2, e3);
      }
      // l-sum on the MFMA pipe: ones-A-frag, every reg = sum_k P[k][q]
      o_l[qc] = __builtin_amdgcn_mfma_f32_16x16x32_f16(vones, pu.v, o_l[qc], 0, 0, 0);
#pragma unroll
      for (int dt = 0; dt < 4; ++dt)
        o[dt][qc] = __builtin_amdgcn_mfma_f32_16x16x32_f16(vf8[dt], pu.v,
                                                           o[dt][qc], 0, 0, 0);
    }
  };

  // ---- prologue: bits(0) FIRST, then stage(0), stage(1).
  unsigned cw0 = bT[n16], cw1 = bT[16 + n16];
  __builtin_amdgcn_sched_barrier(0);
  stage(0, 0);
  stage(1, 1);
  asm volatile("s_waitcnt vmcnt(2)" ::: "memory");
  __builtin_amdgcn_sched_barrier(0);
  __builtin_amdgcn_s_barrier();

  // ---- main loop: bits(t+1) before stage(t+2); end-of-iter vmcnt(4)
#pragma unroll 3
  for (int t = 0; t < 30; ++t) {
    unsigned nw0 = bT[(size_t)(t + 1) * NQ + n16];
    unsigned nw1 = bT[(size_t)(t + 1) * NQ + 16 + n16];
    __builtin_amdgcn_sched_barrier(0);   // pin bits before stage in vm order
    stage(t + 2, (t + 2) % 3);
    compute(t % 3, cw0, cw1);
    cw0 = nw0; cw1 = nw1;
    asm volatile("s_waitcnt vmcnt(4)" ::: "memory");
    __builtin_amdgcn_sched_barrier(0);
    __builtin_amdgcn_s_barrier();
  }
  // t = 30: bits(31), no stage; drain stage(31) (leave bits(31))
  {
    unsigned nw0 = bT[(size_t)31 * NQ + n16];
    unsigned nw1 = bT[(size_t)31 * NQ + 16 + n16];
    __builtin_amdgcn_sched_barrier(0);
    compute(0, cw0, cw1);
    cw0 = nw0; cw1 = nw1;
    asm volatile("s_waitcnt vmcnt(2)" ::: "memory");
    __builtin_amdgcn_sched_barrier(0);
    __builtin_amdgcn_s_barrier();
  }
  // t = 31: compute only
  compute(1, cw0, cw1);

  // ---- direct per-wave store (no cross-wave reduction needed)
  const size_t tile = ((size_t)h * NQT + qt) * NSUP + kp;
#pragma unroll
  for (int qc = 0; qc < 2; ++qc) {
#pragma unroll
    for (int dt = 0; dt < 4; ++dt) {
      union { f16x4 v; f16x2 h[2]; } u;
      u.h[0] = pkrtz(o[dt][qc][0], o[dt][qc][1]);
      u.h[1] = pkrtz(o[dt][qc][2], o[dt][qc][3]);
      *(f16x4*)&Opart[(tile * 32 + qc * 16 + n16) * 64 + dt * 16 + quad * 4] = u.v;
    }
    if (quad == 0) Lpart[tile * 32 + qc * 16 + n16] = o_l[qc][0];
  }
}

// ---------------------------------------------------------------------------
// 4. combine — EXACT round-6 version (part of the 294.1 best).
// ---------------------------------------------------------------------------
__global__ __launch_bounds__(256) void combine_kernel(
    const _Float16* __restrict__ Opart, const float* __restrict__ Lpart,
    const float* __restrict__ xQ, const float* __restrict__ Wg,
    const float* __restrict__ bg, const float* __restrict__ Wo,
    const float* __restrict__ bo, float* __restrict__ out) {
  __shared__ float comb[8][64];
  __shared__ float gred[32][8];
  __shared__ float glds[8][4];
  int nb = blockIdx.x;
  int tid = threadIdx.x;
  int row0 = nb * 8;

  // gates for this block's 8 rows x 4 heads (32 dots, 8-way split each)
  {
    int rh = tid >> 3, c = tid & 7;
    int r = rh >> 2, hh = rh & 3;
    const float* xp = xQ + (size_t)(row0 + r) * 256 + c * 32;
    const float* wp = Wg + hh * 256 + c * 32;
    float s = 0.f;
#pragma unroll
    for (int e = 0; e < 32; ++e) s = fmaf(xp[e], wp[e], s);
    gred[rh][c] = s;
  }
  __syncthreads();
  if (tid < 32) {
    float s = 0.f;
#pragma unroll
    for (int c = 0; c < 8; ++c) s += gred[tid][c];
    glds[tid >> 2][tid & 3] = 1.f / (1.f + __expf(-(s + bg[tid & 3])));
  }
  __syncthreads();

  int qt = nb >> 2, rbase = (nb & 3) * 8;
  {
    int athr = tid & 31, r = tid >> 5;      // 32 a-pairs x 8 rows
    int rl = rbase + r;
    int a0 = athr * 2;
    float c0 = 0.f, c1 = 0.f;
#pragma unroll
    for (int hh = 0; hh < NH; ++hh) {
      size_t t0 = ((size_t)hh * NQT + qt) * NSUP;
      float a0s = 0.f, a1s = 0.f, lt = 0.f;
#pragma unroll
      for (int s = 0; s < NSUP; ++s) {
        size_t t = t0 + s;
        f16x2 v = *(const f16x2*)&Opart[(t * 32 + rl) * 64 + a0];
        a0s += (float)v[0];
        a1s += (float)v[1];
        lt += Lpart[t * 32 + rl];
      }
      float g = glds[r][hh] / lt;
      c0 = fmaf(g, a0s, c0);
      c1 = fmaf(g, a1s, c1);
    }
    comb[r][a0] = c0;
    comb[r][a0 + 1] = c1;
  }
  __syncthreads();

  int j = tid;
  float accv[8];
#pragma unroll
  for (int r = 0; r < 8; ++r) accv[r] = bo[j];
  for (int aa = 0; aa < 64; ++aa) {
    float w = Wo[(size_t)aa * 256 + j];
#pragma unroll
    for (int r = 0; r < 8; ++r) accv[r] = fmaf(comb[r][aa], w, accv[r]);
  }
#pragma unroll
  for (int r = 0; r < 8; ++r)
    out[(size_t)(row0 + r) * 256 + j] = accv[r];
}

// ---------------------------------------------------------------------------
extern "C" void kernel_launch(void* const* d_in, const int* in_sizes, int n_in,
                              void* d_out, int out_size, void* d_ws, size_t ws_size,
                              hipStream_t stream) {
  const float* xQ  = (const float*)d_in[0];
  const float* xK  = (const float*)d_in[1];
  const int*   mask= (const int*)d_in[2];
  const float* Wq  = (const float*)d_in[3];
  const float* Wk  = (const float*)d_in[4];
  const float* Wv  = (const float*)d_in[5];
  const float* Wg  = (const float*)d_in[6];
  const float* bg  = (const float*)d_in[7];
  const float* Wo  = (const float*)d_in[8];
  const float* bo  = (const float*)d_in[9];
  float* out = (float*)d_out;

  char* ws = (char*)d_ws;
  unsigned short* Qp   = (unsigned short*)(ws + 0);         // 2 MB   [H][NQ][64]
  unsigned short* Kp   = (unsigned short*)(ws + 2097152);   // 4 MB   [H][NK][64]
  _Float16*       Vfp  = (_Float16*)(ws + 6291456);         // 4 MB   frag-linear
  unsigned*       bitsT= (unsigned*)(ws + 10485760);        // 4 MB   [word][row]
  float*          Lp   = (float*)(ws + 14680064);           // 512 KB (4096 tiles)
  _Float16*       Op   = (_Float16*)(ws + 15204352);        // 16.8 MB f16
  unsigned short* Wfp  = (unsigned short*)(ws + 33554432);  // 384 KB frag image

  maskbits_kernel<<<dim3(8240), dim3(256), 0, stream>>>(mask, bitsT,
                                                        Wq, Wk, Wv, Wfp);
  proj_kernel<<<dim3(640), dim3(256), 0, stream>>>(xQ, xK, Wfp, Qp, Kp, Vfp);
  attn_kernel<<<dim3(1024), dim3(256), 0, stream>>>(Qp, Kp, Vfp, bitsT, Op, Lp);
  combine_kernel<<<dim3(NQ / 8), dim3(256), 0, stream>>>(Op, Lp, xQ, Wg, bg,
                                                         Wo, bo, out);
}

// Round 14
// 289.516 us; speedup vs baseline: 1.0835x; 1.0047x over previous
//
#include <hip/hip_runtime.h>
#include <hip/hip_bf16.h>

#define NQ 4096
#define NK 8192
#define DQK 256
#define DA 64
#define NH 4
#define DOUT 256
#define NQT (NQ / 32)        // 128 q-tiles of 32
#define NSUP 8               // surviving partials per (h,qt): 8 key-regions
#define LOG2E 1.44269504088896340736f
#define QSCALE (0.125f * LOG2E)   // 1/sqrt(64) * log2(e), folded into Qp

typedef __attribute__((ext_vector_type(8))) short bf16x8;
typedef __attribute__((ext_vector_type(4))) float f32x4;
typedef __attribute__((ext_vector_type(2))) _Float16 f16x2;
typedef __attribute__((ext_vector_type(4))) _Float16 f16x4;
typedef __attribute__((ext_vector_type(8))) _Float16 f16x8;

__device__ inline unsigned short f2bf(float f) {
  union { float f; unsigned u; } v; v.f = f;
  unsigned r = v.u + 0x7fff + ((v.u >> 16) & 1);  // RNE
  return (unsigned short)(r >> 16);
}

__device__ inline f16x2 pkrtz(float a, float b) {
  return __builtin_bit_cast(f16x2, __builtin_amdgcn_cvt_pkrtz(a, b));
}

__device__ inline void gload16(const void* g, void* l) {
  __builtin_amdgcn_global_load_lds(
      (const __attribute__((address_space(1))) void*)g,
      (__attribute__((address_space(3))) void*)l, 16, 0, 0);
}

// ---------------------------------------------------------------------------
// 1. FUSED: blocks 0..47 convert Wq/Wk/Wv (f32) -> Wf, a global bf16 image in
//    EXACT MFMA B-fragment order (16B per (it,nt,lane) frag; 384 KB total,
//    L2-resident). Blocks 48.. do the mask->bitmask transpose.
// ---------------------------------------------------------------------------
__global__ __launch_bounds__(256) void maskbits_kernel(
    const int* __restrict__ mask, unsigned* __restrict__ bitsT,
    const float* __restrict__ Wq, const float* __restrict__ Wk,
    const float* __restrict__ Wv, unsigned short* __restrict__ Wf) {
  int b = blockIdx.x;
  if (b < 48) {
    // ---- W fragment-image converter: 4 blocks per (proj,head) ----
    int p4h = b >> 2;                    // proj*4 + h, 0..11
    int p = p4h >> 2, h = p4h & 3;
    const float* W = (p == 0 ? Wq : (p == 1 ? Wk : Wv)) + (size_t)h * 16384;
    unsigned short* dst = Wf + (size_t)p4h * 16384;
    int q = b & 3, tid = threadIdx.x;
    for (int s = q * 512 + tid; s < (q + 1) * 512; s += 256) {
      int it = s >> 8, rem = s & 255, nt = rem >> 6, lane = rem & 63;
      int k0 = it * 32 + (lane >> 4) * 8;
      int c = nt * 16 + (lane & 15);
      unsigned short tmp[8];
#pragma unroll
      for (int j = 0; j < 8; ++j) tmp[j] = f2bf(W[(size_t)(k0 + j) * 64 + c]);
      *(bf16x8*)&dst[(size_t)s * 8] = *(const bf16x8*)tmp;
    }
    return;
  }
  b -= 48;

  const int NW = 8192 * 4;                       // total waves
  int wid = b * 4 + (threadIdx.x >> 6);
  int lane = threadIdx.x & 63;
  for (int j = 0; j < 2; ++j) {
    int v[8];
#pragma unroll
    for (int u = 0; u < 8; ++u) {
      int c = wid + (j * 8 + u) * NW;   // u64 chunk id: row = c>>7, ch = c&127
      v[u] = mask[(size_t)(c >> 7) * NK + (c & 127) * 64 + lane];
    }
#pragma unroll
    for (int u = 0; u < 8; ++u) {
      unsigned long long bb = __ballot(v[u] != 0);
      int c = wid + (j * 8 + u) * NW;
      int n = c >> 7, ch = c & 127;
      if (lane == 0)  bitsT[(size_t)(2 * ch) * NQ + n] = (unsigned)bb;
      if (lane == 32) bitsT[(size_t)(2 * ch + 1) * NQ + n] = (unsigned)(bb >> 32);
    }
  }
}

// ---------------------------------------------------------------------------
// 2. projections, LDS-FREE + KV-FUSED. Blocks 0..127 = Q; blocks 128..383 =
//    fused K+V: each xK row-fragment is loaded ONCE into registers and feeds
//    BOTH the Wk-image and Wv-image MFMA accumulators. Halves the KV
//    x-stream (64 -> 32 MB). r11's version of this fusion failed only via
//    its 64KB LDS occupancy cap — that cost is gone now (no LDS at all).
// ---------------------------------------------------------------------------
__global__ __launch_bounds__(256) void proj_kernel(
    const float* __restrict__ xQ, const float* __restrict__ xK,
    const unsigned short* __restrict__ Wf,
    unsigned short* __restrict__ Qp, unsigned short* __restrict__ Kp,
    _Float16* __restrict__ Vf) {
  int b = blockIdx.x;
  int lane = threadIdx.x & 63, wv = threadIdx.x >> 6;
  int quad = lane >> 4, n16 = lane & 15;

  if (b < 128) {
    // ---------------- Q path (r13, LDS-free) ----------------
    int h = b >> 5, rb = b & 31;
    const unsigned short* Wfh = Wf + (size_t)h * 16384;   // proj 0
    int r0 = rb * 128 + wv * 32;

    f32x4 acc[2][4];
#pragma unroll
    for (int mt = 0; mt < 2; ++mt)
#pragma unroll
      for (int nt = 0; nt < 4; ++nt)
        acc[mt][nt] = (f32x4){0.f, 0.f, 0.f, 0.f};

#pragma unroll
    for (int it = 0; it < 8; ++it) {
      const int k0 = it * 32;
      bf16x8 af[2];
#pragma unroll
      for (int mt = 0; mt < 2; ++mt) {
        const float* xp = xQ + (size_t)(r0 + mt * 16 + n16) * 256 + k0 + quad * 8;
        const float4 a0 = *(const float4*)xp;
        const float4 a1 = *(const float4*)(xp + 4);
        bf16x8 a;
        a[0] = (short)f2bf(a0.x); a[1] = (short)f2bf(a0.y);
        a[2] = (short)f2bf(a0.z); a[3] = (short)f2bf(a0.w);
        a[4] = (short)f2bf(a1.x); a[5] = (short)f2bf(a1.y);
        a[6] = (short)f2bf(a1.z); a[7] = (short)f2bf(a1.w);
        af[mt] = a;
      }
      bf16x8 bfr[4];
#pragma unroll
      for (int nt = 0; nt < 4; ++nt)
        bfr[nt] = *(const bf16x8*)&Wfh[((size_t)(it * 4 + nt) * 64 + lane) * 8];
#pragma unroll
      for (int mt = 0; mt < 2; ++mt)
#pragma unroll
        for (int nt = 0; nt < 4; ++nt)
          acc[mt][nt] = __builtin_amdgcn_mfma_f32_16x16x32_bf16(
              af[mt], bfr[nt], acc[mt][nt], 0, 0, 0);
    }

    unsigned short* outp = Qp + (size_t)h * NQ * 64;
#pragma unroll
    for (int mt = 0; mt < 2; ++mt)
#pragma unroll
      for (int nt = 0; nt < 4; ++nt)
#pragma unroll
        for (int r = 0; r < 4; ++r) {
          int row = r0 + mt * 16 + quad * 4 + r;
          int col = nt * 16 + n16;
          outp[(size_t)row * 64 + col] = f2bf(acc[mt][nt][r] * QSCALE);
        }
  } else {
    // ---------------- fused K+V path ----------------
    int b2 = b - 128;
    int h = b2 >> 6, rb = b2 & 63;
    const unsigned short* Wfk = Wf + (size_t)(4 + h) * 16384;
    const unsigned short* Wfv = Wf + (size_t)(8 + h) * 16384;
    int r0 = rb * 128 + wv * 32;

    f32x4 accK[2][4], accV[2][4];
#pragma unroll
    for (int mt = 0; mt < 2; ++mt)
#pragma unroll
      for (int nt = 0; nt < 4; ++nt) {
        accK[mt][nt] = (f32x4){0.f, 0.f, 0.f, 0.f};
        accV[mt][nt] = (f32x4){0.f, 0.f, 0.f, 0.f};
      }

#pragma unroll
    for (int it = 0; it < 8; ++it) {
      const int k0 = it * 32;
      bf16x8 af[2];
#pragma unroll
      for (int mt = 0; mt < 2; ++mt) {
        const float* xp = xK + (size_t)(r0 + mt * 16 + n16) * 256 + k0 + quad * 8;
        const float4 a0 = *(const float4*)xp;
        const float4 a1 = *(const float4*)(xp + 4);
        bf16x8 a;
        a[0] = (short)f2bf(a0.x); a[1] = (short)f2bf(a0.y);
        a[2] = (short)f2bf(a0.z); a[3] = (short)f2bf(a0.w);
        a[4] = (short)f2bf(a1.x); a[5] = (short)f2bf(a1.y);
        a[6] = (short)f2bf(a1.z); a[7] = (short)f2bf(a1.w);
        af[mt] = a;
      }
      bf16x8 bK[4], bV[4];
#pragma unroll
      for (int nt = 0; nt < 4; ++nt) {
        bK[nt] = *(const bf16x8*)&Wfk[((size_t)(it * 4 + nt) * 64 + lane) * 8];
        bV[nt] = *(const bf16x8*)&Wfv[((size_t)(it * 4 + nt) * 64 + lane) * 8];
      }
#pragma unroll
      for (int mt = 0; mt < 2; ++mt)
#pragma unroll
        for (int nt = 0; nt < 4; ++nt) {
          accK[mt][nt] = __builtin_amdgcn_mfma_f32_16x16x32_bf16(
              af[mt], bK[nt], accK[mt][nt], 0, 0, 0);
          accV[mt][nt] = __builtin_amdgcn_mfma_f32_16x16x32_bf16(
              af[mt], bV[nt], accV[mt][nt], 0, 0, 0);
        }
    }

    // K epilogue (row-major bf16)
    unsigned short* outp = Kp + (size_t)h * NK * 64;
#pragma unroll
    for (int mt = 0; mt < 2; ++mt)
#pragma unroll
      for (int nt = 0; nt < 4; ++nt)
#pragma unroll
        for (int r = 0; r < 4; ++r) {
          int row = r0 + mt * 16 + quad * 4 + r;
          int col = nt * 16 + n16;
          outp[(size_t)row * 64 + col] = f2bf(accK[mt][nt][r]);
        }

    // V epilogue: K=32 fragment-linear, tile = h*256 + keyblock32
    int tile = h * 256 + (r0 >> 5);
#pragma unroll
    for (int nt = 0; nt < 4; ++nt) {
      f16x8 pk;
      pk[0] = (_Float16)accV[0][nt][0]; pk[1] = (_Float16)accV[0][nt][1];
      pk[2] = (_Float16)accV[0][nt][2]; pk[3] = (_Float16)accV[0][nt][3];
      pk[4] = (_Float16)accV[1][nt][0]; pk[5] = (_Float16)accV[1][nt][1];
      pk[6] = (_Float16)accV[1][nt][2]; pk[7] = (_Float16)accV[1][nt][3];
      *(f16x8*)&Vf[(((size_t)tile * 4 + nt) * 64 + lane) * 8] = pk;
    }
  }
}

// ---------------------------------------------------------------------------
// 3. flash attention — round-12/13 version (ties best measured).
// ---------------------------------------------------------------------------
__global__ __launch_bounds__(256, 4) void attn_kernel(
    const unsigned short* __restrict__ Qp, const unsigned short* __restrict__ Kp,
    const _Float16* __restrict__ Vf, const unsigned* __restrict__ bitsT,
    _Float16* __restrict__ Opart, float* __restrict__ Lpart) {
  __shared__ __align__(16) char lds[3][8192];   // [buf][K 4KB | V 4KB]

  // bijective XCD swizzle (8 XCDs, 1024 blocks, 128/chunk)
  int orig = blockIdx.x;
  int wgid = (orig & 7) * 128 + (orig >> 3);
  int qtg = wgid & 31;
  int combo = wgid >> 5;          // h*8 + kp: each XCD owns 4 combos, same h
  int kp = combo & 7, h = combo >> 3;

  int wv = threadIdx.x >> 6, lane = threadIdx.x & 63;
  int quad = lane >> 4, n16 = lane & 15;
  int qt = qtg * 4 + wv;          // this wave's q-tile
  int qb = qt * 32;

  // Q frags (bf16, pre-scaled by QSCALE)
  bf16x8 qf[2][2];
#pragma unroll
  for (int qc = 0; qc < 2; ++qc)
#pragma unroll
    for (int c = 0; c < 2; ++c)
      qf[qc][c] = *(const bf16x8*)&Qp[((size_t)h * NQ + qb + qc * 16 + n16) * 64 +
                                      c * 32 + quad * 8];

  f32x4 o[4][2];
#pragma unroll
  for (int dt = 0; dt < 4; ++dt)
#pragma unroll
    for (int qc = 0; qc < 2; ++qc) o[dt][qc] = (f32x4){0.f, 0.f, 0.f, 0.f};
  f32x4 o_l[2];
  o_l[0] = (f32x4){0.f, 0.f, 0.f, 0.f};
  o_l[1] = (f32x4){0.f, 0.f, 0.f, 0.f};

  f16x8 vones;
#pragma unroll
  for (int i = 0; i < 8; ++i) vones[i] = (_Float16)1.0f;

  const char* Kreg = (const char*)(Kp + (size_t)h * NK * 64 + (size_t)kp * 1024 * 64);
  const char* Vreg = (const char*)(Vf + ((size_t)h * 256 + kp * 32) * 2048);
  const unsigned* bT = bitsT + (size_t)(kp * 32) * NQ + qb;

  // per-lane source offsets: each wave stages 2 KB of the 8 KB tile image.
  const char* sb;
  int soff[2];
  if (wv < 2) {
    sb = Kreg;
#pragma unroll
    for (int i = 0; i < 2; ++i)
      soff[i] = ((wv * 16 + n16) * 64 + i * 32 + quad * 8) * 2;
  } else {
    sb = Vreg;
#pragma unroll
    for (int i = 0; i < 2; ++i)
      soff[i] = (wv - 2) * 2048 + i * 1024 + lane * 16;
  }

  auto stage = [&](int t, int bufidx) {
    char* d = &lds[bufidx][wv * 2048];
    const char* s0 = sb + (size_t)t * 4096;
#pragma unroll
    for (int i = 0; i < 2; ++i)
      gload16(s0 + soff[i], d + i * 1024);
  };

  auto compute = [&](int buf, unsigned wqa0, unsigned wqa1) {
    const char* Kl = lds[buf];
    const char* Vl = lds[buf] + 4096;

    bf16x8 kf[2][2];
#pragma unroll
    for (int kr = 0; kr < 2; ++kr)
#pragma unroll
      for (int c = 0; c < 2; ++c)
        kf[kr][c] = *(const bf16x8*)(Kl + (kr * 2 + c) * 1024 + lane * 16);

    // S^T = K·Q^T (bf16 K=32, pre-scaled)
    f32x4 s[2][2];
#pragma unroll
    for (int kr = 0; kr < 2; ++kr)
#pragma unroll
      for (int qc = 0; qc < 2; ++qc) {
        f32x4 acc = (f32x4){0.f, 0.f, 0.f, 0.f};
        acc = __builtin_amdgcn_mfma_f32_16x16x32_bf16(kf[kr][0], qf[qc][0], acc, 0, 0, 0);
        acc = __builtin_amdgcn_mfma_f32_16x16x32_bf16(kf[kr][1], qf[qc][1], acc, 0, 0, 0);
        s[kr][qc] = acc;
      }

    f16x8 vf8[4];
#pragma unroll
    for (int dt = 0; dt < 4; ++dt)
      vf8[dt] = *(const f16x8*)(Vl + dt * 1024 + lane * 16);

#pragma unroll
    for (int qc = 0; qc < 2; ++qc) {
      unsigned wq = (qc == 0 ? wqa0 : wqa1) >> (quad * 4);
      union { f16x8 v; f16x2 h[4]; } pu;
#pragma unroll
      for (int kr = 0; kr < 2; ++kr) {
        float e0 = __builtin_amdgcn_exp2f(s[kr][qc][0]);
        float e1 = __builtin_amdgcn_exp2f(s[kr][qc][1]);
        float e2 = __builtin_amdgcn_exp2f(s[kr][qc][2]);
        float e3 = __builtin_amdgcn_exp2f(s[kr][qc][3]);
        e0 = (wq & (1u << (kr * 16 + 0))) ? e0 : 0.f;
        e1 = (wq & (1u << (kr * 16 + 1))) ? e1 : 0.f;
        e2 = (wq & (1u << (kr * 16 + 2))) ? e2 : 0.f;
        e3 = (wq & (1u << (kr * 16 + 3))) ? e3 : 0.f;
        pu.h[kr * 2 + 0] = pkrtz(e0, e1);
        pu.h[kr * 2 + 1] = pkrtz(e2, e3);
      }
      // l-sum on the MFMA pipe: ones-A-frag, every reg = sum_k P[k][q]
      o_l[qc] = __builtin_amdgcn_mfma_f32_16x16x32_f16(vones, pu.v, o_l[qc], 0, 0, 0);
#pragma unroll
      for (int dt = 0; dt < 4; ++dt)
        o[dt][qc] = __builtin_amdgcn_mfma_f32_16x16x32_f16(vf8[dt], pu.v,
                                                           o[dt][qc], 0, 0, 0);
    }
  };

  // ---- prologue: bits(0) FIRST, then stage(0), stage(1).
  unsigned cw0 = bT[n16], cw1 = bT[16 + n16];
  __builtin_amdgcn_sched_barrier(0);
  stage(0, 0);
  stage(1, 1);
  asm volatile("s_waitcnt vmcnt(2)" ::: "memory");
  __builtin_amdgcn_sched_barrier(0);
  __builtin_amdgcn_s_barrier();

  // ---- main loop: bits(t+1) before stage(t+2); end-of-iter vmcnt(4)
#pragma unroll 3
  for (int t = 0; t < 30; ++t) {
    unsigned nw0 = bT[(size_t)(t + 1) * NQ + n16];
    unsigned nw1 = bT[(size_t)(t + 1) * NQ + 16 + n16];
    __builtin_amdgcn_sched_barrier(0);   // pin bits before stage in vm order
    stage(t + 2, (t + 2) % 3);
    compute(t % 3, cw0, cw1);
    cw0 = nw0; cw1 = nw1;
    asm volatile("s_waitcnt vmcnt(4)" ::: "memory");
    __builtin_amdgcn_sched_barrier(0);
    __builtin_amdgcn_s_barrier();
  }
  // t = 30: bits(31), no stage; drain stage(31) (leave bits(31))
  {
    unsigned nw0 = bT[(size_t)31 * NQ + n16];
    unsigned nw1 = bT[(size_t)31 * NQ + 16 + n16];
    __builtin_amdgcn_sched_barrier(0);
    compute(0, cw0, cw1);
    cw0 = nw0; cw1 = nw1;
    asm volatile("s_waitcnt vmcnt(2)" ::: "memory");
    __builtin_amdgcn_sched_barrier(0);
    __builtin_amdgcn_s_barrier();
  }
  // t = 31: compute only
  compute(1, cw0, cw1);

  // ---- direct per-wave store (no cross-wave reduction needed)
  const size_t tile = ((size_t)h * NQT + qt) * NSUP + kp;
#pragma unroll
  for (int qc = 0; qc < 2; ++qc) {
#pragma unroll
    for (int dt = 0; dt < 4; ++dt) {
      union { f16x4 v; f16x2 h[2]; } u;
      u.h[0] = pkrtz(o[dt][qc][0], o[dt][qc][1]);
      u.h[1] = pkrtz(o[dt][qc][2], o[dt][qc][3]);
      *(f16x4*)&Opart[(tile * 32 + qc * 16 + n16) * 64 + dt * 16 + quad * 4] = u.v;
    }
    if (quad == 0) Lpart[tile * 32 + qc * 16 + n16] = o_l[qc][0];
  }
}

// ---------------------------------------------------------------------------
// 4. combine — EXACT round-6 version (part of the best config).
// ---------------------------------------------------------------------------
__global__ __launch_bounds__(256) void combine_kernel(
    const _Float16* __restrict__ Opart, const float* __restrict__ Lpart,
    const float* __restrict__ xQ, const float* __restrict__ Wg,
    const float* __restrict__ bg, const float* __restrict__ Wo,
    const float* __restrict__ bo, float* __restrict__ out) {
  __shared__ float comb[8][64];
  __shared__ float gred[32][8];
  __shared__ float glds[8][4];
  int nb = blockIdx.x;
  int tid = threadIdx.x;
  int row0 = nb * 8;

  // gates for this block's 8 rows x 4 heads (32 dots, 8-way split each)
  {
    int rh = tid >> 3, c = tid & 7;
    int r = rh >> 2, hh = rh & 3;
    const float* xp = xQ + (size_t)(row0 + r) * 256 + c * 32;
    const float* wp = Wg + hh * 256 + c * 32;
    float s = 0.f;
#pragma unroll
    for (int e = 0; e < 32; ++e) s = fmaf(xp[e], wp[e], s);
    gred[rh][c] = s;
  }
  __syncthreads();
  if (tid < 32) {
    float s = 0.f;
#pragma unroll
    for (int c = 0; c < 8; ++c) s += gred[tid][c];
    glds[tid >> 2][tid & 3] = 1.f / (1.f + __expf(-(s + bg[tid & 3])));
  }
  __syncthreads();

  int qt = nb >> 2, rbase = (nb & 3) * 8;
  {
    int athr = tid & 31, r = tid >> 5;      // 32 a-pairs x 8 rows
    int rl = rbase + r;
    int a0 = athr * 2;
    float c0 = 0.f, c1 = 0.f;
#pragma unroll
    for (int hh = 0; hh < NH; ++hh) {
      size_t t0 = ((size_t)hh * NQT + qt) * NSUP;
      float a0s = 0.f, a1s = 0.f, lt = 0.f;
#pragma unroll
      for (int s = 0; s < NSUP; ++s) {
        size_t t = t0 + s;
        f16x2 v = *(const f16x2*)&Opart[(t * 32 + rl) * 64 + a0];
        a0s += (float)v[0];
        a1s += (float)v[1];
        lt += Lpart[t * 32 + rl];
      }
      float g = glds[r][hh] / lt;
      c0 = fmaf(g, a0s, c0);
      c1 = fmaf(g, a1s, c1);
    }
    comb[r][a0] = c0;
    comb[r][a0 + 1] = c1;
  }
  __syncthreads();

  int j = tid;
  float accv[8];
#pragma unroll
  for (int r = 0; r < 8; ++r) accv[r] = bo[j];
  for (int aa = 0; aa < 64; ++aa) {
    float w = Wo[(size_t)aa * 256 + j];
#pragma unroll
    for (int r = 0; r < 8; ++r) accv[r] = fmaf(comb[r][aa], w, accv[r]);
  }
#pragma unroll
  for (int r = 0; r < 8; ++r)
    out[(size_t)(row0 + r) * 256 + j] = accv[r];
}

// ---------------------------------------------------------------------------
extern "C" void kernel_launch(void* const* d_in, const int* in_sizes, int n_in,
                              void* d_out, int out_size, void* d_ws, size_t ws_size,
                              hipStream_t stream) {
  const float* xQ  = (const float*)d_in[0];
  const float* xK  = (const float*)d_in[1];
  const int*   mask= (const int*)d_in[2];
  const float* Wq  = (const float*)d_in[3];
  const float* Wk  = (const float*)d_in[4];
  const float* Wv  = (const float*)d_in[5];
  const float* Wg  = (const float*)d_in[6];
  const float* bg  = (const float*)d_in[7];
  const float* Wo  = (const float*)d_in[8];
  const float* bo  = (const float*)d_in[9];
  float* out = (float*)d_out;

  char* ws = (char*)d_ws;
  unsigned short* Qp   = (unsigned short*)(ws + 0);         // 2 MB   [H][NQ][64]
  unsigned short* Kp   = (unsigned short*)(ws + 2097152);   // 4 MB   [H][NK][64]
  _Float16*       Vfp  = (_Float16*)(ws + 6291456);         // 4 MB   frag-linear
  unsigned*       bitsT= (unsigned*)(ws + 10485760);        // 4 MB   [word][row]
  float*          Lp   = (float*)(ws + 14680064);           // 512 KB (4096 tiles)
  _Float16*       Op   = (_Float16*)(ws + 15204352);        // 16.8 MB f16
  unsigned short* Wfp  = (unsigned short*)(ws + 33554432);  // 384 KB frag image

  maskbits_kernel<<<dim3(8240), dim3(256), 0, stream>>>(mask, bitsT,
                                                        Wq, Wk, Wv, Wfp);
  proj_kernel<<<dim3(384), dim3(256), 0, stream>>>(xQ, xK, Wfp, Qp, Kp, Vfp);
  attn_kernel<<<dim3(1024), dim3(256), 0, stream>>>(Qp, Kp, Vfp, bitsT, Op, Lp);
  combine_kernel<<<dim3(NQ / 8), dim3(256), 0, stream>>>(Op, Lp, xQ, Wg, bg,
                                                         Wo, bo, out);
}